// Round 7
// baseline (562.599 us; speedup 1.0000x reference)
//
#include <hip/hip_runtime.h>
#include <hip/hip_bf16.h>
#include <hip/hip_cooperative_groups.h>
#include <math.h>

namespace cg = cooperative_groups;

#define H 512
#define S 65
#define SP 80                // padded s-dimension (rows 65..79 zero)
#define HS (H * S)           // 33280
#define PHS (H * SP)         // 40960
#define KS3 24
#define KS4 16

// ---------------------------------------------------------------------------
// 64n x 80s x 256k GEMM tile (round-5 proven structure).
// C[s][n] = sum_k yT[s][k] * W[n][k]; x = (ntile | kidx<<3).
// ---------------------------------------------------------------------------
__device__ __forceinline__ void gemm_dev(const float* __restrict__ W,
                                         const float* __restrict__ yT,
                                         float* __restrict__ P,
                                         int x, int tid,
                                         float* __restrict__ Wt,
                                         float* __restrict__ As) {
    int n0   = (x & 7) * 64;
    int kidx = x >> 3;
    int nq = tid & 15;
    int g  = tid >> 4;

    float4 acc[5];
#pragma unroll
    for (int r = 0; r < 5; ++r) acc[r] = make_float4(0.f, 0.f, 0.f, 0.f);

    for (int ch = 0; ch < 4; ++ch) {
        int kc0 = kidx * 256 + ch * 64;
#pragma unroll
        for (int c = 0; c < 4; ++c) {
            int f = c * 256 + tid;
            int wn  = f >> 4;
            int kf4 = f & 15;
            float4 w4 = *(const float4*)(W + (size_t)(n0 + wn) * H + kc0 + 4 * kf4);
            int sw = ((wn >> 2) ^ (kf4 & 7));
            int base = (4 * kf4) * 64 + 4 * sw + (wn & 3);
            Wt[base      ] = w4.x;
            Wt[base +  64] = w4.y;
            Wt[base + 128] = w4.z;
            Wt[base + 192] = w4.w;
        }
#pragma unroll
        for (int c = 0; c < 5; ++c) {
            int f = c * 256 + tid;
            int as  = f >> 4;
            int kf4 = f & 15;
            *(float4*)(&As[as * 64 + 4 * kf4]) =
                *(const float4*)(yT + (size_t)as * H + kc0 + 4 * kf4);
        }
        __syncthreads();

#pragma unroll
        for (int k4 = 0; k4 < 16; ++k4) {
            int swc = 4 * (nq ^ (k4 & 7));
            float4 w0 = *(const float4*)(&Wt[(4 * k4 + 0) * 64 + swc]);
            float4 w1 = *(const float4*)(&Wt[(4 * k4 + 1) * 64 + swc]);
            float4 w2 = *(const float4*)(&Wt[(4 * k4 + 2) * 64 + swc]);
            float4 w3 = *(const float4*)(&Wt[(4 * k4 + 3) * 64 + swc]);
#pragma unroll
            for (int r = 0; r < 5; ++r) {
                float4 a = *(const float4*)(&As[(g + 16 * r) * 64 + 4 * k4]);
                acc[r].x = fmaf(a.x, w0.x, acc[r].x);
                acc[r].y = fmaf(a.x, w0.y, acc[r].y);
                acc[r].z = fmaf(a.x, w0.z, acc[r].z);
                acc[r].w = fmaf(a.x, w0.w, acc[r].w);
                acc[r].x = fmaf(a.y, w1.x, acc[r].x);
                acc[r].y = fmaf(a.y, w1.y, acc[r].y);
                acc[r].z = fmaf(a.y, w1.z, acc[r].z);
                acc[r].w = fmaf(a.y, w1.w, acc[r].w);
                acc[r].x = fmaf(a.z, w2.x, acc[r].x);
                acc[r].y = fmaf(a.z, w2.y, acc[r].y);
                acc[r].z = fmaf(a.z, w2.z, acc[r].z);
                acc[r].w = fmaf(a.z, w2.w, acc[r].w);
                acc[r].x = fmaf(a.w, w3.x, acc[r].x);
                acc[r].y = fmaf(a.w, w3.y, acc[r].y);
                acc[r].z = fmaf(a.w, w3.z, acc[r].z);
                acc[r].w = fmaf(a.w, w3.w, acc[r].w);
            }
        }
        __syncthreads();
    }

#pragma unroll
    for (int r = 0; r < 5; ++r) {
        *(float4*)(P + (size_t)(g + 16 * r) * H + n0 + 4 * nq) = acc[r];
    }
}

// ---------------------------------------------------------------------------
// Attention row a for one head; kqv partial base = kqvp + slot*6*PHS.
// sm carve: ka[0..511], smv[512..576], p[580..645]
// ---------------------------------------------------------------------------
__device__ __forceinline__ void attn_dev(const float* __restrict__ base,
                                         float* __restrict__ aoRow,
                                         int a, int tid,
                                         float* __restrict__ sm) {
    const float* K0 = base;
    const float* K1 = base + PHS;
    const float* Q0 = base + 2 * (size_t)PHS;
    const float* Q1 = base + 3 * (size_t)PHS;
    const float* V0 = base + 4 * (size_t)PHS;
    const float* V1 = base + 5 * (size_t)PHS;
    float* ka  = sm;
    float* smv = sm + 512;
    float* p   = sm + 580;

    ka[tid]       = K0[(size_t)a * H + tid]       + K1[(size_t)a * H + tid];
    ka[tid + 256] = K0[(size_t)a * H + tid + 256] + K1[(size_t)a * H + tid + 256];
    __syncthreads();

    if (tid < S) {
        const float4* q0 = (const float4*)(Q0 + (size_t)tid * H);
        const float4* q1 = (const float4*)(Q1 + (size_t)tid * H);
        const float4* kl = (const float4*)ka;
        float4 c0 = {0,0,0,0}, c1 = {0,0,0,0};
        for (int t = 0; t < H / 4; t += 2) {
            float4 qa = q0[t],     qb = q1[t];
            float4 qc = q0[t + 1], qd = q1[t + 1];
            float4 k0 = kl[t], k1 = kl[t + 1];
            c0.x = fmaf(k0.x, qa.x + qb.x, c0.x);
            c0.y = fmaf(k0.y, qa.y + qb.y, c0.y);
            c0.z = fmaf(k0.z, qa.z + qb.z, c0.z);
            c0.w = fmaf(k0.w, qa.w + qb.w, c0.w);
            c1.x = fmaf(k1.x, qc.x + qd.x, c1.x);
            c1.y = fmaf(k1.y, qc.y + qd.y, c1.y);
            c1.z = fmaf(k1.z, qc.z + qd.z, c1.z);
            c1.w = fmaf(k1.w, qc.w + qd.w, c1.w);
        }
        smv[tid] = ((c0.x + c0.y) + (c0.z + c0.w)) + ((c1.x + c1.y) + (c1.z + c1.w));
    }
    __syncthreads();

    float maxv = -INFINITY;
    for (int i = 0; i < S; ++i) maxv = fmaxf(maxv, smv[i]);
    float sum = 0.0f;
    for (int i = 0; i < S; ++i) sum += expf(smv[i] - maxv);
    float inv = 1.0f / sum;
    if (tid < S) p[tid] = expf(smv[tid] - maxv) * inv;
    __syncthreads();

#pragma unroll
    for (int rep = 0; rep < 2; ++rep) {
        int hh = tid + rep * 256;
        float a0 = 0.f, a1 = 0.f;
#pragma unroll 4
        for (int b = 0; b < 64; b += 2) {
            a0 = fmaf(p[b    ], V0[(size_t)(b    ) * H + hh] + V1[(size_t)(b    ) * H + hh], a0);
            a1 = fmaf(p[b + 1], V0[(size_t)(b + 1) * H + hh] + V1[(size_t)(b + 1) * H + hh], a1);
        }
        a0 = fmaf(p[64], V0[(size_t)64 * H + hh] + V1[(size_t)64 * H + hh], a0);
        aoRow[hh] = a0 + a1;
    }
    __syncthreads();
}

// ---------------------------------------------------------------------------
// Whole network as one cooperative kernel. 256 blocks x 256 threads.
// ---------------------------------------------------------------------------
__global__ void __launch_bounds__(256, 1)
fused_model(const float* __restrict__ inputs, const float* __restrict__ emb,
            const float* __restrict__ wq, const float* __restrict__ wk,
            const float* __restrict__ wv,
            const float* __restrict__ lin1, const float* __restrict__ lin2,
            const float* __restrict__ lin3, const float* __restrict__ lin4,
            const float* __restrict__ lin5, float* __restrict__ out,
            float* __restrict__ yT, float* __restrict__ kqvp,
            float* __restrict__ att1, float* __restrict__ att2,
            float* __restrict__ part1, float* __restrict__ part2,
            float* __restrict__ tpart, float* __restrict__ upart) {
    cg::grid_group grid = cg::this_grid();
    __shared__ __align__(16) float smem[9216];   // 36 KB, reused per stage
    float* Wt = smem;          // 4096 (GEMM)
    float* As = smem + 4096;   // 5120 (GEMM)
    int tid = threadIdx.x;
    int bid = blockIdx.x;

    // ---- stage 0: yT = emb * x (pad rows zero) ----
    if (bid < 160) {
        int i = bid * 256 + tid;
        int s = i / H, h = i % H;
        float v = 0.f;
        if (s < S) {
            float x = (s == 64) ? 1.0f : inputs[s];
            v = emb[h * S + s] * x;
        }
        yT[i] = v;
    }
    grid.sync();

    // ---- stage 1: kqv layer 1 (3 heads, 144 tiles) ----
    if (bid < 144) {
        int x = bid & 15, r = bid >> 4;
        int which = r % 3, slot = r / 3;
        const float* W = (which == 0 ? wk : (which == 1 ? wq : wv)) + (size_t)slot * H * H;
        float* P = kqvp + (size_t)((slot * 3 + which) * 2 + (x >> 3)) * PHS;
        gemm_dev(W, yT, P, x, tid, Wt, As);
    }
    grid.sync();

    // ---- stage 2: attention layer 1 (195 blocks) ----
    if (bid < 195) {
        int slot = bid / 65, a = bid % 65;
        attn_dev(kqvp + (size_t)slot * 6 * PHS,
                 att1 + (size_t)slot * HS + (size_t)a * H, a, tid, smem);
    }
    grid.sync();

    // ---- stage 3: linA (lin1 all 6 segs + lin2 segs 0..3) + lin3 slices 0..15
    for (int vb = bid; vb < 1364; vb += 256) {
        if (vb < 1300) {
            int x = vb % 130, seg = vb / 130;
            int i = x * 256 + tid;
            int s = i / H, h = i % H;
            const float* att;
            const float* L;
            float* dst;
            if (seg < 6) {
                att = att1 + (size_t)(seg >> 1) * HS;
                L   = lin1 + (size_t)(seg * 256) * H + h;
                dst = part1 + (size_t)seg * HS;
            } else {
                int s2 = seg - 6;
                att = att1 + (size_t)(s2 >> 1) * HS;
                L   = lin2 + (size_t)(s2 * 256) * H + h;
                dst = part2 + (size_t)s2 * HS;
            }
            const float* row = att + (size_t)s * H + (seg & 1) * 256;
            float a0 = 0.f, a1 = 0.f, a2 = 0.f, a3 = 0.f;
            for (int j = 0; j < 256; j += 4) {
                a0 = fmaf(row[j + 0], L[(size_t)(j + 0) * H], a0);
                a1 = fmaf(row[j + 1], L[(size_t)(j + 1) * H], a1);
                a2 = fmaf(row[j + 2], L[(size_t)(j + 2) * H], a2);
                a3 = fmaf(row[j + 3], L[(size_t)(j + 3) * H], a3);
            }
            dst[i] = (a0 + a1) + (a2 + a3);
        } else {
            int idx = vb - 1300;                  // 0..63
            int j2 = (idx & 3) * 256 + tid;
            int ks = idx >> 2;                    // 0..15
            const float* row = att1 + (size_t)(ks >> 3) * HS + (size_t)64 * H;
            int j0 = (ks & 7) * 64;
            int jbase = ks * 64;
            float a0 = 0.f, a1 = 0.f, a2 = 0.f, a3 = 0.f;
            for (int j = 0; j < 64; j += 4) {
                a0 = fmaf(row[j0 + j + 0], lin3[(size_t)(jbase + j + 0) * 1024 + j2], a0);
                a1 = fmaf(row[j0 + j + 1], lin3[(size_t)(jbase + j + 1) * 1024 + j2], a1);
                a2 = fmaf(row[j0 + j + 2], lin3[(size_t)(jbase + j + 2) * 1024 + j2], a2);
                a3 = fmaf(row[j0 + j + 3], lin3[(size_t)(jbase + j + 3) * 1024 + j2], a3);
            }
            tpart[ks * 1024 + j2] = (a0 + a1) + (a2 + a3);
        }
    }
    grid.sync();

    // ---- stage 4: combine part1 -> yT (relu) ----
    if (bid < 130) {
        int i = bid * 256 + tid;
        float s = part1[i] + part1[HS + i] + part1[2 * HS + i]
                + part1[3 * HS + i] + part1[4 * HS + i] + part1[5 * HS + i];
        yT[i] = fmaxf(s, 0.0f);
    }
    grid.sync();

    // ---- stage 5: kqv layer 2 head 2 (48 tiles) ----
    if (bid < 48) {
        int x = bid & 15, which = bid >> 4;
        const float* W = (which == 0 ? wk : (which == 1 ? wq : wv)) + (size_t)5 * H * H;
        float* P = kqvp + (size_t)(which * 2 + (x >> 3)) * PHS;
        gemm_dev(W, yT, P, x, tid, Wt, As);
    }
    grid.sync();

    // ---- stage 6: attention layer 2 (65 blocks) ----
    if (bid < 65) {
        attn_dev(kqvp, att2 + (size_t)bid * H, bid, tid, smem);
    }
    grid.sync();

    // ---- stage 7: combine2 fused with lin2 segs 4,5 -> yT (relu) ----
    if (bid < 130) {
        int i = bid * 256 + tid;
        int s = i / H, h = i % H;
        const float* row = att2 + (size_t)s * H;
        const float* L4 = lin2 + (size_t)1024 * H + h;
        const float* L5 = lin2 + (size_t)1280 * H + h;
        float a0 = 0.f, a1 = 0.f, a2 = 0.f, a3 = 0.f;
        for (int j = 0; j < 256; j += 4) {
            a0 = fmaf(row[j + 0], L4[(size_t)(j + 0) * H], a0);
            a1 = fmaf(row[j + 1], L4[(size_t)(j + 1) * H], a1);
            a2 = fmaf(row[j + 2], L4[(size_t)(j + 2) * H], a2);
            a3 = fmaf(row[j + 3], L4[(size_t)(j + 3) * H], a3);
        }
        float s4 = (a0 + a1) + (a2 + a3);
        a0 = a1 = a2 = a3 = 0.f;
        for (int j = 0; j < 256; j += 4) {
            a0 = fmaf(row[256 + j + 0], L5[(size_t)(j + 0) * H], a0);
            a1 = fmaf(row[256 + j + 1], L5[(size_t)(j + 1) * H], a1);
            a2 = fmaf(row[256 + j + 2], L5[(size_t)(j + 2) * H], a2);
            a3 = fmaf(row[256 + j + 3], L5[(size_t)(j + 3) * H], a3);
        }
        float s5 = (a0 + a1) + (a2 + a3);
        float tot = part2[i] + part2[HS + i] + part2[2 * HS + i] + part2[3 * HS + i] + s4 + s5;
        yT[i] = fmaxf(tot, 0.0f);
    }
    grid.sync();

    // ---- stage 8: kqv layer 3 head 2 (48 tiles) ----
    if (bid < 48) {
        int x = bid & 15, which = bid >> 4;
        const float* W = (which == 0 ? wk : (which == 1 ? wq : wv)) + (size_t)8 * H * H;
        float* P = kqvp + (size_t)(which * 2 + (x >> 3)) * PHS;
        gemm_dev(W, yT, P, x, tid, Wt, As);
    }
    grid.sync();

    // ---- stage 9: attn3 row 64 + lin3 slices 16..23 (32 blocks) ----
    if (bid < 32) {
        int jx = bid & 3;
        int ks = 16 + (bid >> 2);
        int j2 = jx * 256 + tid;
        int j0 = (ks & 7) * 64;
        const float* K0 = kqvp;
        const float* K1 = kqvp + PHS;
        const float* Q0 = kqvp + 2 * (size_t)PHS;
        const float* Q1 = kqvp + 3 * (size_t)PHS;
        const float* V0 = kqvp + 4 * (size_t)PHS;
        const float* V1 = kqvp + 5 * (size_t)PHS;
        float* ka    = smem;
        float* smv   = smem + 512;
        float* p     = smem + 580;
        float* att_s = smem + 648;

        ka[tid]       = K0[(size_t)64 * H + tid]       + K1[(size_t)64 * H + tid];
        ka[tid + 256] = K0[(size_t)64 * H + tid + 256] + K1[(size_t)64 * H + tid + 256];
        __syncthreads();

        if (tid < S) {
            const float4* q0 = (const float4*)(Q0 + (size_t)tid * H);
            const float4* q1 = (const float4*)(Q1 + (size_t)tid * H);
            const float4* kl = (const float4*)ka;
            float4 c0 = {0,0,0,0}, c1 = {0,0,0,0};
            for (int t = 0; t < H / 4; t += 2) {
                float4 qa = q0[t],     qb = q1[t];
                float4 qc = q0[t + 1], qd = q1[t + 1];
                float4 k0 = kl[t], k1 = kl[t + 1];
                c0.x = fmaf(k0.x, qa.x + qb.x, c0.x);
                c0.y = fmaf(k0.y, qa.y + qb.y, c0.y);
                c0.z = fmaf(k0.z, qa.z + qb.z, c0.z);
                c0.w = fmaf(k0.w, qa.w + qb.w, c0.w);
                c1.x = fmaf(k1.x, qc.x + qd.x, c1.x);
                c1.y = fmaf(k1.y, qc.y + qd.y, c1.y);
                c1.z = fmaf(k1.z, qc.z + qd.z, c1.z);
                c1.w = fmaf(k1.w, qc.w + qd.w, c1.w);
            }
            smv[tid] = ((c0.x + c0.y) + (c0.z + c0.w)) + ((c1.x + c1.y) + (c1.z + c1.w));
        }
        __syncthreads();

        float maxv = -INFINITY;
        for (int i = 0; i < S; ++i) maxv = fmaxf(maxv, smv[i]);
        float sum = 0.0f;
        for (int i = 0; i < S; ++i) sum += expf(smv[i] - maxv);
        float inv = 1.0f / sum;
        if (tid < S) p[tid] = expf(smv[tid] - maxv) * inv;
        __syncthreads();

        if (tid < 64) {
            int hh = j0 + tid;
            float a0 = 0.f, a1 = 0.f;
#pragma unroll 4
            for (int b = 0; b < 64; b += 2) {
                a0 = fmaf(p[b    ], V0[(size_t)(b    ) * H + hh] + V1[(size_t)(b    ) * H + hh], a0);
                a1 = fmaf(p[b + 1], V0[(size_t)(b + 1) * H + hh] + V1[(size_t)(b + 1) * H + hh], a1);
            }
            a0 = fmaf(p[64], V0[(size_t)64 * H + hh] + V1[(size_t)64 * H + hh], a0);
            att_s[tid] = a0 + a1;
        }
        __syncthreads();

        int jbase = ks * 64;
        float a0 = 0.f, a1 = 0.f, a2 = 0.f, a3 = 0.f;
        for (int j = 0; j < 64; j += 4) {
            a0 = fmaf(att_s[j + 0], lin3[(size_t)(jbase + j + 0) * 1024 + j2], a0);
            a1 = fmaf(att_s[j + 1], lin3[(size_t)(jbase + j + 1) * 1024 + j2], a1);
            a2 = fmaf(att_s[j + 2], lin3[(size_t)(jbase + j + 2) * 1024 + j2], a2);
            a3 = fmaf(att_s[j + 3], lin3[(size_t)(jbase + j + 3) * 1024 + j2], a3);
        }
        tpart[ks * 1024 + j2] = (a0 + a1) + (a2 + a3);
    }
    grid.sync();

    // ---- stage 10: lin4 partials (32 blocks) ----
    if (bid < 32) {
        float* tl = smem;                       // 64
        int hh = (bid & 1) * 256 + tid;
        int ks = bid >> 1;
        int j2base = ks * 64;
        if (tid < 64) {
            int j2 = j2base + tid;
            float s = 0.f;
#pragma unroll
            for (int p = 0; p < KS3; ++p) s += tpart[p * 1024 + j2];
            tl[tid] = fmaxf(s, 0.f);
        }
        __syncthreads();
        float a0 = 0.f, a1 = 0.f, a2 = 0.f, a3 = 0.f;
        for (int j = 0; j < 64; j += 4) {
            a0 = fmaf(tl[j + 0], lin4[(size_t)(j2base + j + 0) * H + hh], a0);
            a1 = fmaf(tl[j + 1], lin4[(size_t)(j2base + j + 1) * H + hh], a1);
            a2 = fmaf(tl[j + 2], lin4[(size_t)(j2base + j + 2) * H + hh], a2);
            a3 = fmaf(tl[j + 3], lin4[(size_t)(j2base + j + 3) * H + hh], a3);
        }
        upart[ks * H + hh] = (a0 + a1) + (a2 + a3);
    }
    grid.sync();

    // ---- stage 11: final (block 0, 256 threads) ----
    if (bid == 0) {
        float* u  = smem;         // 512
        float* pr = smem + 512;   // 256
        float s0 = 0.f, s1 = 0.f;
#pragma unroll
        for (int p = 0; p < KS4; ++p) {
            s0 += upart[p * H + tid];
            s1 += upart[p * H + tid + 256];
        }
        u[tid]       = tanhf(s0);
        u[tid + 256] = tanhf(s1);
        __syncthreads();

        int o  = tid & 63;
        int sl = tid >> 6;        // 4 slices of 128 hh
        float acc = 0.f;
        int h0 = sl * 128;
#pragma unroll 8
        for (int j = 0; j < 128; ++j) {
            acc = fmaf(u[h0 + j], lin5[(h0 + j) * 64 + o], acc);
        }
        pr[sl * 64 + o] = acc;
        __syncthreads();

        if (tid < 64) {
            out[tid] = ((pr[tid] + pr[64 + tid]) + (pr[128 + tid] + pr[192 + tid]));
        }
    }
}

// ---------------------------------------------------------------------------
extern "C" void kernel_launch(void* const* d_in, const int* in_sizes, int n_in,
                              void* d_out, int out_size, void* d_ws, size_t ws_size,
                              hipStream_t stream) {
    const float* inputs  = (const float*)d_in[0];
    const float* emb     = (const float*)d_in[1];
    const float* wq      = (const float*)d_in[2];
    const float* wk      = (const float*)d_in[3];
    const float* wv      = (const float*)d_in[4];
    const float* linear1 = (const float*)d_in[5];
    const float* linear2 = (const float*)d_in[6];
    const float* linear3 = (const float*)d_in[7];
    const float* linear4 = (const float*)d_in[8];
    const float* linear5 = (const float*)d_in[9];
    float* out = (float*)d_out;

    float* ws    = (float*)d_ws;
    float* y     = ws;                  // PHS
    float* kqvp  = y     + PHS;         // 18*PHS
    float* att1  = kqvp  + 18 * PHS;    // 3*HS
    float* att2  = att1  + 3 * HS;      // HS
    float* part1 = att2  + HS;          // 6*HS
    float* part2 = part1 + 6 * HS;      // 4*HS
    float* tpart = part2 + 4 * HS;      // 24*1024
    float* upart = tpart + KS3 * 1024;  // 16*512

    void* args[] = {
        (void*)&inputs, (void*)&emb, (void*)&wq, (void*)&wk, (void*)&wv,
        (void*)&linear1, (void*)&linear2, (void*)&linear3, (void*)&linear4,
        (void*)&linear5, (void*)&out,
        (void*)&y, (void*)&kqvp, (void*)&att1, (void*)&att2,
        (void*)&part1, (void*)&part2, (void*)&tpart, (void*)&upart
    };

    hipLaunchCooperativeKernel((void*)fused_model, dim3(256), dim3(256),
                               args, 0, stream);
}

// Round 8
// 428.693 us; speedup vs baseline: 1.3124x; 1.3124x over previous
//
#include <hip/hip_runtime.h>
#include <hip/hip_bf16.h>
#include <math.h>

#define H 512
#define S 65
#define SP 80                // padded s-dimension (rows 65..79 garbage/zero)
#define HS (H * S)           // 33280
#define PHS (H * SP)         // 40960
#define KS3 24
#define KS4 16

// Layouts:
//  yT:   [SP][H], pad rows zeroed by embed.
//  kqvp: 18 arrays of PHS: ((slot*3 + which)*2 + kidx)*PHS, which 0=k,1=q,2=v.
//  att1: 3 heads x PHS (rows >=65 garbage, never read as output).
//  att2: PHS.
//  plin1/plin2: 12 K-split partials x PHS each.

// ---------------------------------------------------------------------------
__global__ void scale_embed_kernel(const float* __restrict__ inp,
                                   const float* __restrict__ emb,
                                   float* __restrict__ yT) {
    int i = blockIdx.x * blockDim.x + threadIdx.x;
    if (i < PHS) {
        int s = i / H;
        int h = i % H;
        float v = 0.f;
        if (s < S) {
            float x = (s == 64) ? 1.0f : inp[s];
            v = emb[h * S + s] * x;
        }
        yT[i] = v;
    }
}

// ---------------------------------------------------------------------------
// KQV GEMM (round-5/6 proven): C[s][n] = sum_k yT[s][k] * W[n][k]
// grid.x = 8 n-tiles * 2 k-splits; W staged transposed w/ XOR swizzle.
// ---------------------------------------------------------------------------
__global__ void __launch_bounds__(256, 2)
kqv_gemm_tiled(const float* __restrict__ wq,
               const float* __restrict__ wk,
               const float* __restrict__ wv,
               int layer, int head0,
               const float* __restrict__ yT,
               float* __restrict__ part) {
    int slot  = blockIdx.z;
    int which = blockIdx.y;
    int mat = layer * 3 + head0 + slot;
    const float* W = (which == 0 ? wk : (which == 1 ? wq : wv)) + (size_t)mat * H * H;

    int n0   = (blockIdx.x & 7) * 64;
    int kidx = blockIdx.x >> 3;

    __shared__ float Wt[64 * 64];
    __shared__ float As[SP * 64];

    int t  = threadIdx.x;
    int nq = t & 15;
    int g  = t >> 4;

    float4 acc[5];
#pragma unroll
    for (int r = 0; r < 5; ++r) acc[r] = make_float4(0.f, 0.f, 0.f, 0.f);

    for (int ch = 0; ch < 4; ++ch) {
        int kc0 = kidx * 256 + ch * 64;
#pragma unroll
        for (int c = 0; c < 4; ++c) {
            int f = c * 256 + t;
            int wn  = f >> 4;
            int kf4 = f & 15;
            float4 w4 = *(const float4*)(W + (size_t)(n0 + wn) * H + kc0 + 4 * kf4);
            int sw = ((wn >> 2) ^ (kf4 & 7));
            int base = (4 * kf4) * 64 + 4 * sw + (wn & 3);
            Wt[base      ] = w4.x;
            Wt[base +  64] = w4.y;
            Wt[base + 128] = w4.z;
            Wt[base + 192] = w4.w;
        }
#pragma unroll
        for (int c = 0; c < 5; ++c) {
            int f = c * 256 + t;
            int as  = f >> 4;
            int kf4 = f & 15;
            *(float4*)(&As[as * 64 + 4 * kf4]) =
                *(const float4*)(yT + (size_t)as * H + kc0 + 4 * kf4);
        }
        __syncthreads();

#pragma unroll
        for (int k4 = 0; k4 < 16; ++k4) {
            int swc = 4 * (nq ^ (k4 & 7));
            float4 w0 = *(const float4*)(&Wt[(4 * k4 + 0) * 64 + swc]);
            float4 w1 = *(const float4*)(&Wt[(4 * k4 + 1) * 64 + swc]);
            float4 w2 = *(const float4*)(&Wt[(4 * k4 + 2) * 64 + swc]);
            float4 w3 = *(const float4*)(&Wt[(4 * k4 + 3) * 64 + swc]);
#pragma unroll
            for (int r = 0; r < 5; ++r) {
                float4 a = *(const float4*)(&As[(g + 16 * r) * 64 + 4 * k4]);
                acc[r].x = fmaf(a.x, w0.x, acc[r].x);
                acc[r].y = fmaf(a.x, w0.y, acc[r].y);
                acc[r].z = fmaf(a.x, w0.z, acc[r].z);
                acc[r].w = fmaf(a.x, w0.w, acc[r].w);
                acc[r].x = fmaf(a.y, w1.x, acc[r].x);
                acc[r].y = fmaf(a.y, w1.y, acc[r].y);
                acc[r].z = fmaf(a.y, w1.z, acc[r].z);
                acc[r].w = fmaf(a.y, w1.w, acc[r].w);
                acc[r].x = fmaf(a.z, w2.x, acc[r].x);
                acc[r].y = fmaf(a.z, w2.y, acc[r].y);
                acc[r].z = fmaf(a.z, w2.z, acc[r].z);
                acc[r].w = fmaf(a.z, w2.w, acc[r].w);
                acc[r].x = fmaf(a.w, w3.x, acc[r].x);
                acc[r].y = fmaf(a.w, w3.y, acc[r].y);
                acc[r].z = fmaf(a.w, w3.z, acc[r].z);
                acc[r].w = fmaf(a.w, w3.w, acc[r].w);
            }
        }
        __syncthreads();
    }

    float* P = part + (size_t)((slot * 3 + which) * 2 + kidx) * PHS;
#pragma unroll
    for (int r = 0; r < 5; ++r) {
        *(float4*)(P + (size_t)(g + 16 * r) * H + n0 + 4 * nq) = acc[r];
    }
}

// ---------------------------------------------------------------------------
// Score partial: quarter t of dot(ka, q_b) over 2 K-split partials.
// ---------------------------------------------------------------------------
__device__ __forceinline__ float score_part(const float* __restrict__ Q0,
                                            const float* __restrict__ Q1,
                                            const float* __restrict__ ka,
                                            int b, int t) {
    const float4* q0 = (const float4*)(Q0 + (size_t)b * H) + t * 32;
    const float4* q1 = (const float4*)(Q1 + (size_t)b * H) + t * 32;
    const float4* kl = (const float4*)ka + t * 32;
    float4 c0 = {0,0,0,0}, c1 = {0,0,0,0};
#pragma unroll
    for (int u = 0; u < 32; u += 2) {
        float4 qa = q0[u], qb = q1[u], k0 = kl[u];
        float4 qc = q0[u+1], qd = q1[u+1], k1 = kl[u+1];
        c0.x = fmaf(k0.x, qa.x + qb.x, c0.x);
        c0.y = fmaf(k0.y, qa.y + qb.y, c0.y);
        c0.z = fmaf(k0.z, qa.z + qb.z, c0.z);
        c0.w = fmaf(k0.w, qa.w + qb.w, c0.w);
        c1.x = fmaf(k1.x, qc.x + qd.x, c1.x);
        c1.y = fmaf(k1.y, qc.y + qd.y, c1.y);
        c1.z = fmaf(k1.z, qc.z + qd.z, c1.z);
        c1.w = fmaf(k1.w, qc.w + qd.w, c1.w);
    }
    return ((c0.x + c0.y) + (c0.z + c0.w)) + ((c1.x + c1.y) + (c1.z + c1.w));
}

// ---------------------------------------------------------------------------
// Attention row a, head slot; combines the 2 kqv K-split partials inline.
// Scores parallelized over all 256 threads (t = tid>>6 wave-uniform).
// ---------------------------------------------------------------------------
__global__ void attn_kernel(const float* __restrict__ kqvp,
                            float* __restrict__ att) {
    int a = blockIdx.x;
    int slot = blockIdx.y;
    int tid = threadIdx.x;   // 256

    const float* base = kqvp + (size_t)slot * 6 * PHS;
    const float* K0 = base;
    const float* K1 = base + PHS;
    const float* Q0 = base + 2 * (size_t)PHS;
    const float* Q1 = base + 3 * (size_t)PHS;
    const float* V0 = base + 4 * (size_t)PHS;
    const float* V1 = base + 5 * (size_t)PHS;
    float* ao = att + (size_t)slot * PHS + (size_t)a * H;

    __shared__ float ka[H];
    __shared__ float sp[4 * 65];
    __shared__ float smv[S];
    __shared__ float p[S];

    ka[tid]       = K0[(size_t)a * H + tid]       + K1[(size_t)a * H + tid];
    ka[tid + 256] = K0[(size_t)a * H + tid + 256] + K1[(size_t)a * H + tid + 256];
    __syncthreads();

    {
        int b = tid & 63;
        int t = tid >> 6;          // wave-uniform
        sp[t * 65 + b] = score_part(Q0, Q1, ka, b, t);
        if (tid < 4) sp[tid * 65 + 64] = score_part(Q0, Q1, ka, 64, tid);
    }
    __syncthreads();

    if (tid < S) {
        smv[tid] = (sp[tid] + sp[65 + tid]) + (sp[130 + tid] + sp[195 + tid]);
    }
    __syncthreads();

    float maxv = -INFINITY;
    for (int i = 0; i < S; ++i) maxv = fmaxf(maxv, smv[i]);
    float sum = 0.0f;
    for (int i = 0; i < S; ++i) sum += expf(smv[i] - maxv);
    float inv = 1.0f / sum;
    if (tid < S) p[tid] = expf(smv[tid] - maxv) * inv;
    __syncthreads();

#pragma unroll
    for (int rep = 0; rep < 2; ++rep) {
        int hh = tid + rep * 256;
        float a0 = 0.f, a1 = 0.f;
#pragma unroll 4
        for (int b = 0; b < 64; b += 2) {
            a0 = fmaf(p[b    ], V0[(size_t)(b    ) * H + hh] + V1[(size_t)(b    ) * H + hh], a0);
            a1 = fmaf(p[b + 1], V0[(size_t)(b + 1) * H + hh] + V1[(size_t)(b + 1) * H + hh], a1);
        }
        a0 = fmaf(p[64], V0[(size_t)64 * H + hh] + V1[(size_t)64 * H + hh], a0);
        ao[hh] = a0 + a1;
    }
}

// ---------------------------------------------------------------------------
// Linear GEMM tile: C[s][n] = sum_k Acat[s][k] * L[k][n]  (L already [k][n]).
// Tile 64n x 80s x 128k (2 chunks). A rows select att head by global k:
// head = kg>>9 -> A01 + head*PHS (head<2) else A2.
// As padded to stride 68 (bank-conflict-free). Output P + kidx*PHS.
// ---------------------------------------------------------------------------
__device__ __forceinline__ void lin_gemm_dev(const float* __restrict__ A01,
                                             const float* __restrict__ A2,
                                             const float* __restrict__ L,
                                             float* __restrict__ Pbase,
                                             int ntile, int kidx, int kbase,
                                             int tid,
                                             float* __restrict__ Bs,
                                             float* __restrict__ As) {
    int n0 = ntile * 64;
    int nq = tid & 15;
    int g  = tid >> 4;

    float4 acc[5];
#pragma unroll
    for (int r = 0; r < 5; ++r) acc[r] = make_float4(0.f, 0.f, 0.f, 0.f);

#pragma unroll
    for (int ch = 0; ch < 2; ++ch) {
        int kg = kbase + kidx * 128 + ch * 64;
        int head = kg >> 9;
        const float* Asrc = (head < 2) ? (A01 + (size_t)head * PHS) : A2;
        int col0 = kg & 511;

#pragma unroll
        for (int c = 0; c < 4; ++c) {
            int f = c * 256 + tid;
            int kk  = f >> 4;
            int hf4 = f & 15;
            *(float4*)(&Bs[kk * 64 + 4 * hf4]) =
                *(const float4*)(L + (size_t)(kg + kk) * H + n0 + 4 * hf4);
        }
#pragma unroll
        for (int c = 0; c < 5; ++c) {
            int f = c * 256 + tid;
            int as  = f >> 4;
            int kf4 = f & 15;
            *(float4*)(&As[as * 68 + 4 * kf4]) =
                *(const float4*)(Asrc + (size_t)as * H + col0 + 4 * kf4);
        }
        __syncthreads();

#pragma unroll
        for (int k4 = 0; k4 < 16; ++k4) {
            float4 w0 = *(const float4*)(&Bs[(4 * k4 + 0) * 64 + 4 * nq]);
            float4 w1 = *(const float4*)(&Bs[(4 * k4 + 1) * 64 + 4 * nq]);
            float4 w2 = *(const float4*)(&Bs[(4 * k4 + 2) * 64 + 4 * nq]);
            float4 w3 = *(const float4*)(&Bs[(4 * k4 + 3) * 64 + 4 * nq]);
#pragma unroll
            for (int r = 0; r < 5; ++r) {
                float4 a = *(const float4*)(&As[(g + 16 * r) * 68 + 4 * k4]);
                acc[r].x = fmaf(a.x, w0.x, acc[r].x);
                acc[r].y = fmaf(a.x, w0.y, acc[r].y);
                acc[r].z = fmaf(a.x, w0.z, acc[r].z);
                acc[r].w = fmaf(a.x, w0.w, acc[r].w);
                acc[r].x = fmaf(a.y, w1.x, acc[r].x);
                acc[r].y = fmaf(a.y, w1.y, acc[r].y);
                acc[r].z = fmaf(a.y, w1.z, acc[r].z);
                acc[r].w = fmaf(a.y, w1.w, acc[r].w);
                acc[r].x = fmaf(a.z, w2.x, acc[r].x);
                acc[r].y = fmaf(a.z, w2.y, acc[r].y);
                acc[r].z = fmaf(a.z, w2.z, acc[r].z);
                acc[r].w = fmaf(a.z, w2.w, acc[r].w);
                acc[r].x = fmaf(a.w, w3.x, acc[r].x);
                acc[r].y = fmaf(a.w, w3.y, acc[r].y);
                acc[r].z = fmaf(a.w, w3.z, acc[r].z);
                acc[r].w = fmaf(a.w, w3.w, acc[r].w);
            }
        }
        __syncthreads();
    }

    float* P = Pbase + (size_t)kidx * PHS;
#pragma unroll
    for (int r = 0; r < 5; ++r) {
        *(float4*)(P + (size_t)(g + 16 * r) * H + n0 + 4 * nq) = acc[r];
    }
}

// ---------------------------------------------------------------------------
// lin1 GEMM (96 blocks) + lin3 row-64 slices 0..15 (64 blocks) in one grid.
// ---------------------------------------------------------------------------
__global__ void __launch_bounds__(256, 2)
lin1plus_kernel(const float* __restrict__ att1,
                const float* __restrict__ lin1,
                const float* __restrict__ lin3,
                float* __restrict__ plin1,
                float* __restrict__ tpart) {
    __shared__ float Bs[64 * 64];
    __shared__ float As[SP * 68];
    int bx = blockIdx.x;
    int tid = threadIdx.x;

    if (bx < 96) {
        lin_gemm_dev(att1, att1 + 2 * (size_t)PHS, lin1, plin1,
                     bx & 7, bx >> 3, 0, tid, Bs, As);
    } else {
        int idx = bx - 96;                    // 0..63
        int j2 = (idx & 3) * 256 + tid;
        int ks = idx >> 2;                    // 0..15
        const float* row = att1 + (size_t)(ks >> 3) * PHS + (size_t)64 * H;
        int j0 = (ks & 7) * 64;
        int jbase = ks * 64;
        float a0 = 0.f, a1 = 0.f, a2 = 0.f, a3 = 0.f;
        for (int j = 0; j < 64; j += 4) {
            a0 = fmaf(row[j0 + j + 0], lin3[(size_t)(jbase + j + 0) * 1024 + j2], a0);
            a1 = fmaf(row[j0 + j + 1], lin3[(size_t)(jbase + j + 1) * 1024 + j2], a1);
            a2 = fmaf(row[j0 + j + 2], lin3[(size_t)(jbase + j + 2) * 1024 + j2], a2);
            a3 = fmaf(row[j0 + j + 3], lin3[(size_t)(jbase + j + 3) * 1024 + j2], a3);
        }
        tpart[ks * 1024 + j2] = (a0 + a1) + (a2 + a3);
    }
}

// lin2 K-rows 0..1023 from att1 (8 K-splits, 64 blocks) -> plin2[0..7]
__global__ void __launch_bounds__(256, 2)
lin2ab_kernel(const float* __restrict__ att1,
              const float* __restrict__ lin2,
              float* __restrict__ plin2) {
    __shared__ float Bs[64 * 64];
    __shared__ float As[SP * 68];
    int bx = blockIdx.x;
    lin_gemm_dev(att1, att1, lin2, plin2, bx & 7, bx >> 3, 0,
                 threadIdx.x, Bs, As);
}

// lin2 K-rows 1024..1535 from att2 (4 K-splits, 32 blocks) -> plin2[8..11]
__global__ void __launch_bounds__(256, 2)
lin2c_kernel(const float* __restrict__ att2,
             const float* __restrict__ lin2,
             float* __restrict__ plin2) {
    __shared__ float Bs[64 * 64];
    __shared__ float As[SP * 68];
    int bx = blockIdx.x;
    lin_gemm_dev(att2, att2, lin2, plin2 + 8 * (size_t)PHS,
                 bx & 7, bx >> 3, 1024, threadIdx.x, Bs, As);
}

// 12-way partial sum + relu -> yT rows s<65 (pad rows stay zero from embed)
__global__ void combine12_relu_kernel(const float* __restrict__ part,
                                      float* __restrict__ yT) {
    int i = blockIdx.x * 256 + threadIdx.x;
    float s = 0.f;
#pragma unroll
    for (int p = 0; p < 12; ++p) s += part[(size_t)p * PHS + i];
    yT[i] = fmaxf(s, 0.0f);
}

// ---------------------------------------------------------------------------
// Layer-3 attention (row 64 only) + lin3 slices 16..23. 32 blocks.
// ---------------------------------------------------------------------------
__global__ void attn3_lin3c_kernel(const float* __restrict__ kqvp,
                                   const float* __restrict__ lin3,
                                   float* __restrict__ tpart) {
    int tid = threadIdx.x;
    int ks  = 16 + blockIdx.y;                 // 16..23
    int j2  = blockIdx.x * 256 + tid;
    int j0  = (ks & 7) * 64;

    const float* K0 = kqvp;
    const float* K1 = kqvp + PHS;
    const float* Q0 = kqvp + 2 * (size_t)PHS;
    const float* Q1 = kqvp + 3 * (size_t)PHS;
    const float* V0 = kqvp + 4 * (size_t)PHS;
    const float* V1 = kqvp + 5 * (size_t)PHS;

    __shared__ float ka[H];
    __shared__ float sp[4 * 65];
    __shared__ float smv[S];
    __shared__ float p[S];
    __shared__ float att_s[64];

    ka[tid]       = K0[(size_t)64 * H + tid]       + K1[(size_t)64 * H + tid];
    ka[tid + 256] = K0[(size_t)64 * H + tid + 256] + K1[(size_t)64 * H + tid + 256];
    __syncthreads();

    {
        int b = tid & 63;
        int t = tid >> 6;
        sp[t * 65 + b] = score_part(Q0, Q1, ka, b, t);
        if (tid < 4) sp[tid * 65 + 64] = score_part(Q0, Q1, ka, 64, tid);
    }
    __syncthreads();

    if (tid < S) {
        smv[tid] = (sp[tid] + sp[65 + tid]) + (sp[130 + tid] + sp[195 + tid]);
    }
    __syncthreads();

    float maxv = -INFINITY;
    for (int i = 0; i < S; ++i) maxv = fmaxf(maxv, smv[i]);
    float sum = 0.0f;
    for (int i = 0; i < S; ++i) sum += expf(smv[i] - maxv);
    float inv = 1.0f / sum;
    if (tid < S) p[tid] = expf(smv[tid] - maxv) * inv;
    __syncthreads();

    if (tid < 64) {
        int hh = j0 + tid;
        float a0 = 0.f, a1 = 0.f;
#pragma unroll 4
        for (int b = 0; b < 64; b += 2) {
            a0 = fmaf(p[b    ], V0[(size_t)(b    ) * H + hh] + V1[(size_t)(b    ) * H + hh], a0);
            a1 = fmaf(p[b + 1], V0[(size_t)(b + 1) * H + hh] + V1[(size_t)(b + 1) * H + hh], a1);
        }
        a0 = fmaf(p[64], V0[(size_t)64 * H + hh] + V1[(size_t)64 * H + hh], a0);
        att_s[tid] = a0 + a1;
    }
    __syncthreads();

    int jbase = ks * 64;
    float a0 = 0.f, a1 = 0.f, a2 = 0.f, a3 = 0.f;
    for (int j = 0; j < 64; j += 4) {
        a0 = fmaf(att_s[j + 0], lin3[(size_t)(jbase + j + 0) * 1024 + j2], a0);
        a1 = fmaf(att_s[j + 1], lin3[(size_t)(jbase + j + 1) * 1024 + j2], a1);
        a2 = fmaf(att_s[j + 2], lin3[(size_t)(jbase + j + 2) * 1024 + j2], a2);
        a3 = fmaf(att_s[j + 3], lin3[(size_t)(jbase + j + 3) * 1024 + j2], a3);
    }
    tpart[ks * 1024 + j2] = (a0 + a1) + (a2 + a3);
}

// ---------------------------------------------------------------------------
__global__ void lin4_partial_kernel(const float* __restrict__ tpart,
                                    const float* __restrict__ lin4,
                                    float* __restrict__ upart) {
    __shared__ float tl[64];
    int hh = blockIdx.x * 256 + threadIdx.x;
    int ks = blockIdx.y;
    int j2base = ks * 64;

    if (threadIdx.x < 64) {
        int j2 = j2base + threadIdx.x;
        float s = 0.f;
#pragma unroll
        for (int p = 0; p < KS3; ++p) s += tpart[p * 1024 + j2];
        tl[threadIdx.x] = fmaxf(s, 0.f);
    }
    __syncthreads();

    float a0 = 0.f, a1 = 0.f, a2 = 0.f, a3 = 0.f;
    for (int j = 0; j < 64; j += 4) {
        a0 = fmaf(tl[j + 0], lin4[(size_t)(j2base + j + 0) * H + hh], a0);
        a1 = fmaf(tl[j + 1], lin4[(size_t)(j2base + j + 1) * H + hh], a1);
        a2 = fmaf(tl[j + 2], lin4[(size_t)(j2base + j + 2) * H + hh], a2);
        a3 = fmaf(tl[j + 3], lin4[(size_t)(j2base + j + 3) * H + hh], a3);
    }
    upart[ks * H + hh] = (a0 + a1) + (a2 + a3);
}

__global__ void final_out_kernel(const float* __restrict__ upart,
                                 const float* __restrict__ lin5,
                                 float* __restrict__ out) {
    __shared__ float u[H];
    __shared__ float pr[8][64];
    int tid = threadIdx.x;   // 512

    {
        float s = 0.f;
#pragma unroll
        for (int p = 0; p < KS4; ++p) s += upart[p * H + tid];
        u[tid] = tanhf(s);
    }
    __syncthreads();

    int o  = tid & 63;
    int sl = tid >> 6;
    float acc = 0.f;
    int h0 = sl * 64;
#pragma unroll 8
    for (int j = 0; j < 64; ++j) {
        acc = fmaf(u[h0 + j], lin5[(h0 + j) * 64 + o], acc);
    }
    pr[sl][o] = acc;
    __syncthreads();

    if (tid < 64) {
        float s = 0.f;
#pragma unroll
        for (int p = 0; p < 8; ++p) s += pr[p][tid];
        out[tid] = s;
    }
}

// ---------------------------------------------------------------------------
extern "C" void kernel_launch(void* const* d_in, const int* in_sizes, int n_in,
                              void* d_out, int out_size, void* d_ws, size_t ws_size,
                              hipStream_t stream) {
    const float* inputs  = (const float*)d_in[0];
    const float* emb     = (const float*)d_in[1];
    const float* wq      = (const float*)d_in[2];
    const float* wk      = (const float*)d_in[3];
    const float* wv      = (const float*)d_in[4];
    const float* linear1 = (const float*)d_in[5];
    const float* linear2 = (const float*)d_in[6];
    const float* linear3 = (const float*)d_in[7];
    const float* linear4 = (const float*)d_in[8];
    const float* linear5 = (const float*)d_in[9];
    float* out = (float*)d_out;

    float* ws    = (float*)d_ws;
    float* y     = ws;                  // PHS
    float* kqvp  = y     + PHS;         // 18*PHS
    float* att1  = kqvp  + 18 * PHS;    // 3*PHS
    float* att2  = att1  + 3 * PHS;     // PHS
    float* plin1 = att2  + PHS;         // 12*PHS
    float* plin2 = plin1 + 12 * PHS;    // 12*PHS
    float* tpart = plin2 + 12 * PHS;    // 24*1024
    float* upart = tpart + KS3 * 1024;  // 16*512

    const int nb  = HS / 256;           // 130
    const int nbp = PHS / 256;          // 160

    scale_embed_kernel<<<nbp, 256, 0, stream>>>(inputs, emb, y);

    // ---- Layer 1 ----
    kqv_gemm_tiled<<<dim3(16, 3, 3), 256, 0, stream>>>(wq, wk, wv, 0, 0, y, kqvp);
    attn_kernel<<<dim3(S, 3), 256, 0, stream>>>(kqvp, att1);
    lin1plus_kernel<<<160, 256, 0, stream>>>(att1, linear1, linear3, plin1, tpart);
    lin2ab_kernel<<<64, 256, 0, stream>>>(att1, linear2, plin2);
    combine12_relu_kernel<<<nb, 256, 0, stream>>>(plin1, y);

    // ---- Layer 2 (head 2 only) ----
    kqv_gemm_tiled<<<dim3(16, 3, 1), 256, 0, stream>>>(wq, wk, wv, 1, 2, y, kqvp);
    attn_kernel<<<dim3(S, 1), 256, 0, stream>>>(kqvp, att2);
    lin2c_kernel<<<32, 256, 0, stream>>>(att2, linear2, plin2);
    combine12_relu_kernel<<<nb, 256, 0, stream>>>(plin2, y);

    // ---- Layer 3 (head 2, row 64) + lin3 tail ----
    kqv_gemm_tiled<<<dim3(16, 3, 1), 256, 0, stream>>>(wq, wk, wv, 2, 2, y, kqvp);
    attn3_lin3c_kernel<<<dim3(4, 8), 256, 0, stream>>>(kqvp, linear3, tpart);

    // ---- Final ----
    lin4_partial_kernel<<<dim3(2, KS4), 256, 0, stream>>>(tpart, linear4, upart);
    final_out_kernel<<<1, 512, 0, stream>>>(upart, linear5, out);
}

// Round 9
// 304.563 us; speedup vs baseline: 1.8472x; 1.4076x over previous
//
#include <hip/hip_runtime.h>
#include <hip/hip_bf16.h>
#include <math.h>

#define H 512
#define S 65
#define SP 80                // padded s-dimension (rows 65..79 garbage/zero)
#define HS (H * S)           // 33280
#define PHS (H * SP)         // 40960
#define KS3 24
#define KS4 16

// Layouts:
//  yT:   [SP][H], pad rows zeroed by embed.
//  kqvp: 18 arrays of PHS: ((slot*3 + which)*2 + kidx)*PHS, which 0=k,1=q,2=v.
//  att1: 3 heads x PHS (rows >=65 garbage, never read as final output).
//  att2: PHS.
//  plin1/plin2: 12 K-split partials x PHS each.

// ---------------------------------------------------------------------------
__global__ void scale_embed_kernel(const float* __restrict__ inp,
                                   const float* __restrict__ emb,
                                   float* __restrict__ yT) {
    int i = blockIdx.x * blockDim.x + threadIdx.x;
    if (i < PHS) {
        int s = i / H;
        int h = i % H;
        float v = 0.f;
        if (s < S) {
            float x = (s == 64) ? 1.0f : inp[s];
            v = emb[h * S + s] * x;
        }
        yT[i] = v;
    }
}

// ---------------------------------------------------------------------------
// KQV GEMM (round-5/6 proven): C[s][n] = sum_k yT[s][k] * W[n][k]
// ---------------------------------------------------------------------------
__global__ void __launch_bounds__(256, 2)
kqv_gemm_tiled(const float* __restrict__ wq,
               const float* __restrict__ wk,
               const float* __restrict__ wv,
               int layer, int head0,
               const float* __restrict__ yT,
               float* __restrict__ part) {
    int slot  = blockIdx.z;
    int which = blockIdx.y;
    int mat = layer * 3 + head0 + slot;
    const float* W = (which == 0 ? wk : (which == 1 ? wq : wv)) + (size_t)mat * H * H;

    int n0   = (blockIdx.x & 7) * 64;
    int kidx = blockIdx.x >> 3;

    __shared__ float Wt[64 * 64];
    __shared__ float As[SP * 64];

    int t  = threadIdx.x;
    int nq = t & 15;
    int g  = t >> 4;

    float4 acc[5];
#pragma unroll
    for (int r = 0; r < 5; ++r) acc[r] = make_float4(0.f, 0.f, 0.f, 0.f);

    for (int ch = 0; ch < 4; ++ch) {
        int kc0 = kidx * 256 + ch * 64;
#pragma unroll
        for (int c = 0; c < 4; ++c) {
            int f = c * 256 + t;
            int wn  = f >> 4;
            int kf4 = f & 15;
            float4 w4 = *(const float4*)(W + (size_t)(n0 + wn) * H + kc0 + 4 * kf4);
            int sw = ((wn >> 2) ^ (kf4 & 7));
            int base = (4 * kf4) * 64 + 4 * sw + (wn & 3);
            Wt[base      ] = w4.x;
            Wt[base +  64] = w4.y;
            Wt[base + 128] = w4.z;
            Wt[base + 192] = w4.w;
        }
#pragma unroll
        for (int c = 0; c < 5; ++c) {
            int f = c * 256 + t;
            int as  = f >> 4;
            int kf4 = f & 15;
            *(float4*)(&As[as * 64 + 4 * kf4]) =
                *(const float4*)(yT + (size_t)as * H + kc0 + 4 * kf4);
        }
        __syncthreads();

#pragma unroll
        for (int k4 = 0; k4 < 16; ++k4) {
            int swc = 4 * (nq ^ (k4 & 7));
            float4 w0 = *(const float4*)(&Wt[(4 * k4 + 0) * 64 + swc]);
            float4 w1 = *(const float4*)(&Wt[(4 * k4 + 1) * 64 + swc]);
            float4 w2 = *(const float4*)(&Wt[(4 * k4 + 2) * 64 + swc]);
            float4 w3 = *(const float4*)(&Wt[(4 * k4 + 3) * 64 + swc]);
#pragma unroll
            for (int r = 0; r < 5; ++r) {
                float4 a = *(const float4*)(&As[(g + 16 * r) * 64 + 4 * k4]);
                acc[r].x = fmaf(a.x, w0.x, acc[r].x);
                acc[r].y = fmaf(a.x, w0.y, acc[r].y);
                acc[r].z = fmaf(a.x, w0.z, acc[r].z);
                acc[r].w = fmaf(a.x, w0.w, acc[r].w);
                acc[r].x = fmaf(a.y, w1.x, acc[r].x);
                acc[r].y = fmaf(a.y, w1.y, acc[r].y);
                acc[r].z = fmaf(a.y, w1.z, acc[r].z);
                acc[r].w = fmaf(a.y, w1.w, acc[r].w);
                acc[r].x = fmaf(a.z, w2.x, acc[r].x);
                acc[r].y = fmaf(a.z, w2.y, acc[r].y);
                acc[r].z = fmaf(a.z, w2.z, acc[r].z);
                acc[r].w = fmaf(a.z, w2.w, acc[r].w);
                acc[r].x = fmaf(a.w, w3.x, acc[r].x);
                acc[r].y = fmaf(a.w, w3.y, acc[r].y);
                acc[r].z = fmaf(a.w, w3.z, acc[r].z);
                acc[r].w = fmaf(a.w, w3.w, acc[r].w);
            }
        }
        __syncthreads();
    }

    float* P = part + (size_t)((slot * 3 + which) * 2 + kidx) * PHS;
#pragma unroll
    for (int r = 0; r < 5; ++r) {
        *(float4*)(P + (size_t)(g + 16 * r) * H + n0 + 4 * nq) = acc[r];
    }
}

// ---------------------------------------------------------------------------
__device__ __forceinline__ float score_part(const float* __restrict__ Q0,
                                            const float* __restrict__ Q1,
                                            const float* __restrict__ ka,
                                            int b, int t) {
    const float4* q0 = (const float4*)(Q0 + (size_t)b * H) + t * 32;
    const float4* q1 = (const float4*)(Q1 + (size_t)b * H) + t * 32;
    const float4* kl = (const float4*)ka + t * 32;
    float4 c0 = {0,0,0,0}, c1 = {0,0,0,0};
#pragma unroll
    for (int u = 0; u < 32; u += 2) {
        float4 qa = q0[u], qb = q1[u], k0 = kl[u];
        float4 qc = q0[u+1], qd = q1[u+1], k1 = kl[u+1];
        c0.x = fmaf(k0.x, qa.x + qb.x, c0.x);
        c0.y = fmaf(k0.y, qa.y + qb.y, c0.y);
        c0.z = fmaf(k0.z, qa.z + qb.z, c0.z);
        c0.w = fmaf(k0.w, qa.w + qb.w, c0.w);
        c1.x = fmaf(k1.x, qc.x + qd.x, c1.x);
        c1.y = fmaf(k1.y, qc.y + qd.y, c1.y);
        c1.z = fmaf(k1.z, qc.z + qd.z, c1.z);
        c1.w = fmaf(k1.w, qc.w + qd.w, c1.w);
    }
    return ((c0.x + c0.y) + (c0.z + c0.w)) + ((c1.x + c1.y) + (c1.z + c1.w));
}

// ---------------------------------------------------------------------------
__global__ void attn_kernel(const float* __restrict__ kqvp,
                            float* __restrict__ att) {
    int a = blockIdx.x;
    int slot = blockIdx.y;
    int tid = threadIdx.x;   // 256

    const float* base = kqvp + (size_t)slot * 6 * PHS;
    const float* K0 = base;
    const float* K1 = base + PHS;
    const float* Q0 = base + 2 * (size_t)PHS;
    const float* Q1 = base + 3 * (size_t)PHS;
    const float* V0 = base + 4 * (size_t)PHS;
    const float* V1 = base + 5 * (size_t)PHS;
    float* ao = att + (size_t)slot * PHS + (size_t)a * H;

    __shared__ float ka[H];
    __shared__ float sp[4 * 65];
    __shared__ float smv[S];
    __shared__ float p[S];

    ka[tid]       = K0[(size_t)a * H + tid]       + K1[(size_t)a * H + tid];
    ka[tid + 256] = K0[(size_t)a * H + tid + 256] + K1[(size_t)a * H + tid + 256];
    __syncthreads();

    {
        int b = tid & 63;
        int t = tid >> 6;          // wave-uniform
        sp[t * 65 + b] = score_part(Q0, Q1, ka, b, t);
        if (tid < 4) sp[tid * 65 + 64] = score_part(Q0, Q1, ka, 64, tid);
    }
    __syncthreads();

    if (tid < S) {
        smv[tid] = (sp[tid] + sp[65 + tid]) + (sp[130 + tid] + sp[195 + tid]);
    }
    __syncthreads();

    float maxv = -INFINITY;
    for (int i = 0; i < S; ++i) maxv = fmaxf(maxv, smv[i]);
    float sum = 0.0f;
    for (int i = 0; i < S; ++i) sum += expf(smv[i] - maxv);
    float inv = 1.0f / sum;
    if (tid < S) p[tid] = expf(smv[tid] - maxv) * inv;
    __syncthreads();

#pragma unroll
    for (int rep = 0; rep < 2; ++rep) {
        int hh = tid + rep * 256;
        float a0 = 0.f, a1 = 0.f;
#pragma unroll 4
        for (int b = 0; b < 64; b += 2) {
            a0 = fmaf(p[b    ], V0[(size_t)(b    ) * H + hh] + V1[(size_t)(b    ) * H + hh], a0);
            a1 = fmaf(p[b + 1], V0[(size_t)(b + 1) * H + hh] + V1[(size_t)(b + 1) * H + hh], a1);
        }
        a0 = fmaf(p[64], V0[(size_t)64 * H + hh] + V1[(size_t)64 * H + hh], a0);
        ao[hh] = a0 + a1;
    }
}

// ---------------------------------------------------------------------------
// Linear GEMM tile: C[s][n] = sum_k Acat[s][k] * L[k][n]  (L already [k][n]).
// ---------------------------------------------------------------------------
__device__ __forceinline__ void lin_gemm_dev(const float* __restrict__ A01,
                                             const float* __restrict__ A2,
                                             const float* __restrict__ L,
                                             float* __restrict__ Pbase,
                                             int ntile, int kidx, int kbase,
                                             int tid,
                                             float* __restrict__ Bs,
                                             float* __restrict__ As) {
    int n0 = ntile * 64;
    int nq = tid & 15;
    int g  = tid >> 4;

    float4 acc[5];
#pragma unroll
    for (int r = 0; r < 5; ++r) acc[r] = make_float4(0.f, 0.f, 0.f, 0.f);

#pragma unroll
    for (int ch = 0; ch < 2; ++ch) {
        int kg = kbase + kidx * 128 + ch * 64;
        int head = kg >> 9;
        const float* Asrc = (head < 2) ? (A01 + (size_t)head * PHS) : A2;
        int col0 = kg & 511;

#pragma unroll
        for (int c = 0; c < 4; ++c) {
            int f = c * 256 + tid;
            int kk  = f >> 4;
            int hf4 = f & 15;
            *(float4*)(&Bs[kk * 64 + 4 * hf4]) =
                *(const float4*)(L + (size_t)(kg + kk) * H + n0 + 4 * hf4);
        }
#pragma unroll
        for (int c = 0; c < 5; ++c) {
            int f = c * 256 + tid;
            int as  = f >> 4;
            int kf4 = f & 15;
            *(float4*)(&As[as * 68 + 4 * kf4]) =
                *(const float4*)(Asrc + (size_t)as * H + col0 + 4 * kf4);
        }
        __syncthreads();

#pragma unroll
        for (int k4 = 0; k4 < 16; ++k4) {
            float4 w0 = *(const float4*)(&Bs[(4 * k4 + 0) * 64 + 4 * nq]);
            float4 w1 = *(const float4*)(&Bs[(4 * k4 + 1) * 64 + 4 * nq]);
            float4 w2 = *(const float4*)(&Bs[(4 * k4 + 2) * 64 + 4 * nq]);
            float4 w3 = *(const float4*)(&Bs[(4 * k4 + 3) * 64 + 4 * nq]);
#pragma unroll
            for (int r = 0; r < 5; ++r) {
                float4 a = *(const float4*)(&As[(g + 16 * r) * 68 + 4 * k4]);
                acc[r].x = fmaf(a.x, w0.x, acc[r].x);
                acc[r].y = fmaf(a.x, w0.y, acc[r].y);
                acc[r].z = fmaf(a.x, w0.z, acc[r].z);
                acc[r].w = fmaf(a.x, w0.w, acc[r].w);
                acc[r].x = fmaf(a.y, w1.x, acc[r].x);
                acc[r].y = fmaf(a.y, w1.y, acc[r].y);
                acc[r].z = fmaf(a.y, w1.z, acc[r].z);
                acc[r].w = fmaf(a.y, w1.w, acc[r].w);
                acc[r].x = fmaf(a.z, w2.x, acc[r].x);
                acc[r].y = fmaf(a.z, w2.y, acc[r].y);
                acc[r].z = fmaf(a.z, w2.z, acc[r].z);
                acc[r].w = fmaf(a.z, w2.w, acc[r].w);
                acc[r].x = fmaf(a.w, w3.x, acc[r].x);
                acc[r].y = fmaf(a.w, w3.y, acc[r].y);
                acc[r].z = fmaf(a.w, w3.z, acc[r].z);
                acc[r].w = fmaf(a.w, w3.w, acc[r].w);
            }
        }
        __syncthreads();
    }

    float* P = Pbase + (size_t)kidx * PHS;
#pragma unroll
    for (int r = 0; r < 5; ++r) {
        *(float4*)(P + (size_t)(g + 16 * r) * H + n0 + 4 * nq) = acc[r];
    }
}

// ---------------------------------------------------------------------------
// lin1 GEMM (96 blocks) + lin3 row-64 slices 0..15 (64 blocks).
// __launch_bounds__(256,1): 512-VGPR budget -> no spill (round-8 bug: the
// (256,2) variant let the allocator target 4 waves/EU, cap 128, and spill).
// ---------------------------------------------------------------------------
__global__ void __launch_bounds__(256, 1)
lin1plus_kernel(const float* __restrict__ att1,
                const float* __restrict__ lin1,
                const float* __restrict__ lin3,
                float* __restrict__ plin1,
                float* __restrict__ tpart) {
    __shared__ float Bs[64 * 64];
    __shared__ float As[SP * 68];
    int bx = blockIdx.x;
    int tid = threadIdx.x;

    if (bx < 96) {
        lin_gemm_dev(att1, att1 + 2 * (size_t)PHS, lin1, plin1,
                     bx & 7, bx >> 3, 0, tid, Bs, As);
    } else {
        int idx = bx - 96;                    // 0..63
        int j2 = (idx & 3) * 256 + tid;
        int ks = idx >> 2;                    // 0..15
        const float* row = att1 + (size_t)(ks >> 3) * PHS + (size_t)64 * H;
        int j0 = (ks & 7) * 64;
        int jbase = ks * 64;
        float a0 = 0.f, a1 = 0.f, a2 = 0.f, a3 = 0.f;
        for (int j = 0; j < 64; j += 4) {
            a0 = fmaf(row[j0 + j + 0], lin3[(size_t)(jbase + j + 0) * 1024 + j2], a0);
            a1 = fmaf(row[j0 + j + 1], lin3[(size_t)(jbase + j + 1) * 1024 + j2], a1);
            a2 = fmaf(row[j0 + j + 2], lin3[(size_t)(jbase + j + 2) * 1024 + j2], a2);
            a3 = fmaf(row[j0 + j + 3], lin3[(size_t)(jbase + j + 3) * 1024 + j2], a3);
        }
        tpart[ks * 1024 + j2] = (a0 + a1) + (a2 + a3);
    }
}

// lin2 K-rows 0..1023 from att1 (8 K-splits, 64 blocks) -> plin2[0..7]
__global__ void __launch_bounds__(256, 1)
lin2ab_kernel(const float* __restrict__ att1,
              const float* __restrict__ lin2,
              float* __restrict__ plin2) {
    __shared__ float Bs[64 * 64];
    __shared__ float As[SP * 68];
    int bx = blockIdx.x;
    lin_gemm_dev(att1, att1, lin2, plin2, bx & 7, bx >> 3, 0,
                 threadIdx.x, Bs, As);
}

// lin2 K-rows 1024..1535 from att2 (4 K-splits, 32 blocks) -> plin2[8..11]
__global__ void __launch_bounds__(256, 1)
lin2c_kernel(const float* __restrict__ att2,
             const float* __restrict__ lin2,
             float* __restrict__ plin2) {
    __shared__ float Bs[64 * 64];
    __shared__ float As[SP * 68];
    int bx = blockIdx.x;
    lin_gemm_dev(att2, att2, lin2, plin2 + 8 * (size_t)PHS,
                 bx & 7, bx >> 3, 1024, threadIdx.x, Bs, As);
}

// 12-way partial sum + relu -> yT rows s<65 (pad rows stay zero from embed)
__global__ void combine12_relu_kernel(const float* __restrict__ part,
                                      float* __restrict__ yT) {
    int i = blockIdx.x * 256 + threadIdx.x;
    float s = 0.f;
#pragma unroll
    for (int p = 0; p < 12; ++p) s += part[(size_t)p * PHS + i];
    yT[i] = fmaxf(s, 0.0f);
}

// ---------------------------------------------------------------------------
// Layer-3 attention (row 64 only) + lin3 slices 16..23. 32 blocks.
// ---------------------------------------------------------------------------
__global__ void attn3_lin3c_kernel(const float* __restrict__ kqvp,
                                   const float* __restrict__ lin3,
                                   float* __restrict__ tpart) {
    int tid = threadIdx.x;
    int ks  = 16 + blockIdx.y;                 // 16..23
    int j2  = blockIdx.x * 256 + tid;
    int j0  = (ks & 7) * 64;

    const float* K0 = kqvp;
    const float* K1 = kqvp + PHS;
    const float* Q0 = kqvp + 2 * (size_t)PHS;
    const float* Q1 = kqvp + 3 * (size_t)PHS;
    const float* V0 = kqvp + 4 * (size_t)PHS;
    const float* V1 = kqvp + 5 * (size_t)PHS;

    __shared__ float ka[H];
    __shared__ float sp[4 * 65];
    __shared__ float smv[S];
    __shared__ float p[S];
    __shared__ float att_s[64];

    ka[tid]       = K0[(size_t)64 * H + tid]       + K1[(size_t)64 * H + tid];
    ka[tid + 256] = K0[(size_t)64 * H + tid + 256] + K1[(size_t)64 * H + tid + 256];
    __syncthreads();

    {
        int b = tid & 63;
        int t = tid >> 6;
        sp[t * 65 + b] = score_part(Q0, Q1, ka, b, t);
        if (tid < 4) sp[tid * 65 + 64] = score_part(Q0, Q1, ka, 64, tid);
    }
    __syncthreads();

    if (tid < S) {
        smv[tid] = (sp[tid] + sp[65 + tid]) + (sp[130 + tid] + sp[195 + tid]);
    }
    __syncthreads();

    float maxv = -INFINITY;
    for (int i = 0; i < S; ++i) maxv = fmaxf(maxv, smv[i]);
    float sum = 0.0f;
    for (int i = 0; i < S; ++i) sum += expf(smv[i] - maxv);
    float inv = 1.0f / sum;
    if (tid < S) p[tid] = expf(smv[tid] - maxv) * inv;
    __syncthreads();

    if (tid < 64) {
        int hh = j0 + tid;
        float a0 = 0.f, a1 = 0.f;
#pragma unroll 4
        for (int b = 0; b < 64; b += 2) {
            a0 = fmaf(p[b    ], V0[(size_t)(b    ) * H + hh] + V1[(size_t)(b    ) * H + hh], a0);
            a1 = fmaf(p[b + 1], V0[(size_t)(b + 1) * H + hh] + V1[(size_t)(b + 1) * H + hh], a1);
        }
        a0 = fmaf(p[64], V0[(size_t)64 * H + hh] + V1[(size_t)64 * H + hh], a0);
        att_s[tid] = a0 + a1;
    }
    __syncthreads();

    int jbase = ks * 64;
    float a0 = 0.f, a1 = 0.f, a2 = 0.f, a3 = 0.f;
    for (int j = 0; j < 64; j += 4) {
        a0 = fmaf(att_s[j + 0], lin3[(size_t)(jbase + j + 0) * 1024 + j2], a0);
        a1 = fmaf(att_s[j + 1], lin3[(size_t)(jbase + j + 1) * 1024 + j2], a1);
        a2 = fmaf(att_s[j + 2], lin3[(size_t)(jbase + j + 2) * 1024 + j2], a2);
        a3 = fmaf(att_s[j + 3], lin3[(size_t)(jbase + j + 3) * 1024 + j2], a3);
    }
    tpart[ks * 1024 + j2] = (a0 + a1) + (a2 + a3);
}

// ---------------------------------------------------------------------------
__global__ void lin4_partial_kernel(const float* __restrict__ tpart,
                                    const float* __restrict__ lin4,
                                    float* __restrict__ upart) {
    __shared__ float tl[64];
    int hh = blockIdx.x * 256 + threadIdx.x;
    int ks = blockIdx.y;
    int j2base = ks * 64;

    if (threadIdx.x < 64) {
        int j2 = j2base + threadIdx.x;
        float s = 0.f;
#pragma unroll
        for (int p = 0; p < KS3; ++p) s += tpart[p * 1024 + j2];
        tl[threadIdx.x] = fmaxf(s, 0.f);
    }
    __syncthreads();

    float a0 = 0.f, a1 = 0.f, a2 = 0.f, a3 = 0.f;
    for (int j = 0; j < 64; j += 4) {
        a0 = fmaf(tl[j + 0], lin4[(size_t)(j2base + j + 0) * H + hh], a0);
        a1 = fmaf(tl[j + 1], lin4[(size_t)(j2base + j + 1) * H + hh], a1);
        a2 = fmaf(tl[j + 2], lin4[(size_t)(j2base + j + 2) * H + hh], a2);
        a3 = fmaf(tl[j + 3], lin4[(size_t)(j2base + j + 3) * H + hh], a3);
    }
    upart[ks * H + hh] = (a0 + a1) + (a2 + a3);
}

__global__ void final_out_kernel(const float* __restrict__ upart,
                                 const float* __restrict__ lin5,
                                 float* __restrict__ out) {
    __shared__ float u[H];
    __shared__ float pr[8][64];
    int tid = threadIdx.x;   // 512

    {
        float s = 0.f;
#pragma unroll
        for (int p = 0; p < KS4; ++p) s += upart[p * H + tid];
        u[tid] = tanhf(s);
    }
    __syncthreads();

    int o  = tid & 63;
    int sl = tid >> 6;
    float acc = 0.f;
    int h0 = sl * 64;
#pragma unroll 8
    for (int j = 0; j < 64; ++j) {
        acc = fmaf(u[h0 + j], lin5[(h0 + j) * 64 + o], acc);
    }
    pr[sl][o] = acc;
    __syncthreads();

    if (tid < 64) {
        float s = 0.f;
#pragma unroll
        for (int p = 0; p < 8; ++p) s += pr[p][tid];
        out[tid] = s;
    }
}

// ---------------------------------------------------------------------------
extern "C" void kernel_launch(void* const* d_in, const int* in_sizes, int n_in,
                              void* d_out, int out_size, void* d_ws, size_t ws_size,
                              hipStream_t stream) {
    const float* inputs  = (const float*)d_in[0];
    const float* emb     = (const float*)d_in[1];
    const float* wq      = (const float*)d_in[2];
    const float* wk      = (const float*)d_in[3];
    const float* wv      = (const float*)d_in[4];
    const float* linear1 = (const float*)d_in[5];
    const float* linear2 = (const float*)d_in[6];
    const float* linear3 = (const float*)d_in[7];
    const float* linear4 = (const float*)d_in[8];
    const float* linear5 = (const float*)d_in[9];
    float* out = (float*)d_out;

    float* ws    = (float*)d_ws;
    float* y     = ws;                  // PHS
    float* kqvp  = y     + PHS;         // 18*PHS
    float* att1  = kqvp  + 18 * PHS;    // 3*PHS
    float* att2  = att1  + 3 * PHS;     // PHS
    float* plin1 = att2  + PHS;         // 12*PHS
    float* plin2 = plin1 + 12 * PHS;    // 12*PHS
    float* tpart = plin2 + 12 * PHS;    // 24*1024
    float* upart = tpart + KS3 * 1024;  // 16*512

    const int nb  = HS / 256;           // 130
    const int nbp = PHS / 256;          // 160

    scale_embed_kernel<<<nbp, 256, 0, stream>>>(inputs, emb, y);

    // ---- Layer 1 ----
    kqv_gemm_tiled<<<dim3(16, 3, 3), 256, 0, stream>>>(wq, wk, wv, 0, 0, y, kqvp);
    attn_kernel<<<dim3(S, 3), 256, 0, stream>>>(kqvp, att1);
    lin1plus_kernel<<<160, 256, 0, stream>>>(att1, linear1, linear3, plin1, tpart);
    lin2ab_kernel<<<64, 256, 0, stream>>>(att1, linear2, plin2);
    combine12_relu_kernel<<<nb, 256, 0, stream>>>(plin1, y);

    // ---- Layer 2 (head 2 only) ----
    kqv_gemm_tiled<<<dim3(16, 3, 1), 256, 0, stream>>>(wq, wk, wv, 1, 2, y, kqvp);
    attn_kernel<<<dim3(S, 1), 256, 0, stream>>>(kqvp, att2);
    lin2c_kernel<<<32, 256, 0, stream>>>(att2, linear2, plin2);
    combine12_relu_kernel<<<nb, 256, 0, stream>>>(plin2, y);

    // ---- Layer 3 (head 2, row 64) + lin3 tail ----
    kqv_gemm_tiled<<<dim3(16, 3, 1), 256, 0, stream>>>(wq, wk, wv, 2, 2, y, kqvp);
    attn3_lin3c_kernel<<<dim3(4, 8), 256, 0, stream>>>(kqvp, linear3, tpart);

    // ---- Final ----
    lin4_partial_kernel<<<dim3(2, KS4), 256, 0, stream>>>(tpart, linear4, upart);
    final_out_kernel<<<1, 512, 0, stream>>>(upart, linear5, out);
}

// Round 10
// 260.385 us; speedup vs baseline: 2.1606x; 1.1697x over previous
//
#include <hip/hip_runtime.h>
#include <hip/hip_bf16.h>
#include <math.h>

#define H 512
#define S 65
#define SP 80                // padded s-dimension (rows 65..79 zero / poison->relu 0)
#define HS (H * S)           // 33280
#define PHS (H * SP)         // 40960
#define KS3 24
#define KS4 16

// Layouts:
//  yT:   [SP][H], pad rows zeroed by embed.
//  kqvp: 18 arrays of PHS: ((slot*3 + which)*2 + kidx)*PHS, which 0=k,1=q,2=v.
//  att1: 3 heads x PHS; att2: PHS (rows >=65 never written -> poison, never read).
//  plin1: 6 partials x PHS (lin1 segs).  plin2: 6 partials x PHS (lin2 segs).
//  Pad rows of plin* are poison (0xAA = small NEGATIVE float); the inline
//  combine+relu in kqv maps them to 0, which is the correct pad value.

// ---------------------------------------------------------------------------
__global__ void scale_embed_kernel(const float* __restrict__ inp,
                                   const float* __restrict__ emb,
                                   float* __restrict__ yT) {
    int i = blockIdx.x * blockDim.x + threadIdx.x;
    if (i < PHS) {
        int s = i / H;
        int h = i % H;
        float v = 0.f;
        if (s < S) {
            float x = (s == 64) ? 1.0f : inp[s];
            v = emb[h * S + s] * x;
        }
        yT[i] = v;
    }
}

// ---------------------------------------------------------------------------
// KQV GEMM. C[s][n] = sum_k A[s][k] * W[n][k].
// COMBINE=0: A = src (yT).  COMBINE=1: A = relu(sum of 6 PHS-strided partials).
// __launch_bounds__(256,1): spill-proof (rounds 4/8 lesson: capped budgets spill).
// ---------------------------------------------------------------------------
template <int COMBINE>
__global__ void __launch_bounds__(256, 1)
kqv_gemm_tiled(const float* __restrict__ wq,
               const float* __restrict__ wk,
               const float* __restrict__ wv,
               int mat0,
               const float* __restrict__ src,
               float* __restrict__ part) {
    int slot  = blockIdx.z;
    int which = blockIdx.y;
    int mat = mat0 + slot;
    const float* W = (which == 0 ? wk : (which == 1 ? wq : wv)) + (size_t)mat * H * H;

    int n0   = (blockIdx.x & 7) * 64;
    int kidx = blockIdx.x >> 3;

    __shared__ float Wt[64 * 64];
    __shared__ float As[SP * 64];

    int t  = threadIdx.x;
    int nq = t & 15;
    int g  = t >> 4;

    float4 acc[5];
#pragma unroll
    for (int r = 0; r < 5; ++r) acc[r] = make_float4(0.f, 0.f, 0.f, 0.f);

    for (int ch = 0; ch < 4; ++ch) {
        int kc0 = kidx * 256 + ch * 64;
#pragma unroll
        for (int c = 0; c < 4; ++c) {
            int f = c * 256 + t;
            int wn  = f >> 4;
            int kf4 = f & 15;
            float4 w4 = *(const float4*)(W + (size_t)(n0 + wn) * H + kc0 + 4 * kf4);
            int sw = ((wn >> 2) ^ (kf4 & 7));
            int base = (4 * kf4) * 64 + 4 * sw + (wn & 3);
            Wt[base      ] = w4.x;
            Wt[base +  64] = w4.y;
            Wt[base + 128] = w4.z;
            Wt[base + 192] = w4.w;
        }
#pragma unroll
        for (int c = 0; c < 5; ++c) {
            int f = c * 256 + t;
            int as  = f >> 4;
            int kf4 = f & 15;
            const float* addr = src + (size_t)as * H + kc0 + 4 * kf4;
            float4 v;
            if (COMBINE) {
                v = make_float4(0.f, 0.f, 0.f, 0.f);
#pragma unroll
                for (int p = 0; p < 6; ++p) {
                    float4 u = *(const float4*)(addr + (size_t)p * PHS);
                    v.x += u.x; v.y += u.y; v.z += u.z; v.w += u.w;
                }
                v.x = fmaxf(v.x, 0.f); v.y = fmaxf(v.y, 0.f);
                v.z = fmaxf(v.z, 0.f); v.w = fmaxf(v.w, 0.f);
            } else {
                v = *(const float4*)addr;
            }
            *(float4*)(&As[as * 64 + 4 * kf4]) = v;
        }
        __syncthreads();

#pragma unroll
        for (int k4 = 0; k4 < 16; ++k4) {
            int swc = 4 * (nq ^ (k4 & 7));
            float4 w0 = *(const float4*)(&Wt[(4 * k4 + 0) * 64 + swc]);
            float4 w1 = *(const float4*)(&Wt[(4 * k4 + 1) * 64 + swc]);
            float4 w2 = *(const float4*)(&Wt[(4 * k4 + 2) * 64 + swc]);
            float4 w3 = *(const float4*)(&Wt[(4 * k4 + 3) * 64 + swc]);
#pragma unroll
            for (int r = 0; r < 5; ++r) {
                float4 a = *(const float4*)(&As[(g + 16 * r) * 64 + 4 * k4]);
                acc[r].x = fmaf(a.x, w0.x, acc[r].x);
                acc[r].y = fmaf(a.x, w0.y, acc[r].y);
                acc[r].z = fmaf(a.x, w0.z, acc[r].z);
                acc[r].w = fmaf(a.x, w0.w, acc[r].w);
                acc[r].x = fmaf(a.y, w1.x, acc[r].x);
                acc[r].y = fmaf(a.y, w1.y, acc[r].y);
                acc[r].z = fmaf(a.y, w1.z, acc[r].z);
                acc[r].w = fmaf(a.y, w1.w, acc[r].w);
                acc[r].x = fmaf(a.z, w2.x, acc[r].x);
                acc[r].y = fmaf(a.z, w2.y, acc[r].y);
                acc[r].z = fmaf(a.z, w2.z, acc[r].z);
                acc[r].w = fmaf(a.z, w2.w, acc[r].w);
                acc[r].x = fmaf(a.w, w3.x, acc[r].x);
                acc[r].y = fmaf(a.w, w3.y, acc[r].y);
                acc[r].z = fmaf(a.w, w3.z, acc[r].z);
                acc[r].w = fmaf(a.w, w3.w, acc[r].w);
            }
        }
        __syncthreads();
    }

    float* P = part + (size_t)((slot * 3 + which) * 2 + kidx) * PHS;
#pragma unroll
    for (int r = 0; r < 5; ++r) {
        *(float4*)(P + (size_t)(g + 16 * r) * H + n0 + 4 * nq) = acc[r];
    }
}

// ---------------------------------------------------------------------------
__device__ __forceinline__ float score_part(const float* __restrict__ Q0,
                                            const float* __restrict__ Q1,
                                            const float* __restrict__ ka,
                                            int b, int t) {
    const float4* q0 = (const float4*)(Q0 + (size_t)b * H) + t * 32;
    const float4* q1 = (const float4*)(Q1 + (size_t)b * H) + t * 32;
    const float4* kl = (const float4*)ka + t * 32;
    float4 c0 = {0,0,0,0}, c1 = {0,0,0,0};
#pragma unroll
    for (int u = 0; u < 32; u += 2) {
        float4 qa = q0[u], qb = q1[u], k0 = kl[u];
        float4 qc = q0[u+1], qd = q1[u+1], k1 = kl[u+1];
        c0.x = fmaf(k0.x, qa.x + qb.x, c0.x);
        c0.y = fmaf(k0.y, qa.y + qb.y, c0.y);
        c0.z = fmaf(k0.z, qa.z + qb.z, c0.z);
        c0.w = fmaf(k0.w, qa.w + qb.w, c0.w);
        c1.x = fmaf(k1.x, qc.x + qd.x, c1.x);
        c1.y = fmaf(k1.y, qc.y + qd.y, c1.y);
        c1.z = fmaf(k1.z, qc.z + qd.z, c1.z);
        c1.w = fmaf(k1.w, qc.w + qd.w, c1.w);
    }
    return ((c0.x + c0.y) + (c0.z + c0.w)) + ((c1.x + c1.y) + (c1.z + c1.w));
}

// ---------------------------------------------------------------------------
__global__ void attn_kernel(const float* __restrict__ kqvp,
                            float* __restrict__ att) {
    int a = blockIdx.x;
    int slot = blockIdx.y;
    int tid = threadIdx.x;   // 256

    const float* base = kqvp + (size_t)slot * 6 * PHS;
    const float* K0 = base;
    const float* K1 = base + PHS;
    const float* Q0 = base + 2 * (size_t)PHS;
    const float* Q1 = base + 3 * (size_t)PHS;
    const float* V0 = base + 4 * (size_t)PHS;
    const float* V1 = base + 5 * (size_t)PHS;
    float* ao = att + (size_t)slot * PHS + (size_t)a * H;

    __shared__ float ka[H];
    __shared__ float sp[4 * 65];
    __shared__ float smv[S];
    __shared__ float p[S];

    ka[tid]       = K0[(size_t)a * H + tid]       + K1[(size_t)a * H + tid];
    ka[tid + 256] = K0[(size_t)a * H + tid + 256] + K1[(size_t)a * H + tid + 256];
    __syncthreads();

    {
        int b = tid & 63;
        int t = tid >> 6;          // wave-uniform
        sp[t * 65 + b] = score_part(Q0, Q1, ka, b, t);
        if (tid < 4) sp[tid * 65 + 64] = score_part(Q0, Q1, ka, 64, tid);
    }
    __syncthreads();

    if (tid < S) {
        smv[tid] = (sp[tid] + sp[65 + tid]) + (sp[130 + tid] + sp[195 + tid]);
    }
    __syncthreads();

    float maxv = -INFINITY;
    for (int i = 0; i < S; ++i) maxv = fmaxf(maxv, smv[i]);
    float sum = 0.0f;
    for (int i = 0; i < S; ++i) sum += expf(smv[i] - maxv);
    float inv = 1.0f / sum;
    if (tid < S) p[tid] = expf(smv[tid] - maxv) * inv;
    __syncthreads();

#pragma unroll
    for (int rep = 0; rep < 2; ++rep) {
        int hh = tid + rep * 256;
        float a0 = 0.f, a1 = 0.f;
#pragma unroll 4
        for (int b = 0; b < 64; b += 2) {
            a0 = fmaf(p[b    ], V0[(size_t)(b    ) * H + hh] + V1[(size_t)(b    ) * H + hh], a0);
            a1 = fmaf(p[b + 1], V0[(size_t)(b + 1) * H + hh] + V1[(size_t)(b + 1) * H + hh], a1);
        }
        a0 = fmaf(p[64], V0[(size_t)64 * H + hh] + V1[(size_t)64 * H + hh], a0);
        ao[hh] = a0 + a1;
    }
}

// ---------------------------------------------------------------------------
// Mega linear kernel (thread-per-output, round-6 proven form), 1364 blocks:
//  bx <  780 : lin1 seg 0..5  from att1           -> plin1[seg]
//  bx < 1300 : lin2 seg 0..3  from att1 (A,A,B,B) -> plin2[seg]
//  else      : lin3 row-64 K-slices 0..15          -> tpart
// ---------------------------------------------------------------------------
__global__ void mega_lin_kernel(const float* __restrict__ att1,
                                const float* __restrict__ lin1,
                                const float* __restrict__ lin2,
                                const float* __restrict__ lin3,
                                float* __restrict__ plin1,
                                float* __restrict__ plin2,
                                float* __restrict__ tpart) {
    int bx = blockIdx.x;
    int tid = threadIdx.x;

    if (bx < 1300) {
        const float* att;
        const float* L;
        float* dst;
        int x, seg;
        if (bx < 780) {
            seg = bx / 130; x = bx - seg * 130;
            att = att1 + (size_t)(seg >> 1) * PHS;
            L   = lin1 + (size_t)(seg * 256) * H;
            dst = plin1 + (size_t)seg * PHS;
        } else {
            int b2 = bx - 780;
            seg = b2 / 130; x = b2 - seg * 130;          // seg 0..3
            att = att1 + (size_t)(seg >> 1) * PHS;       // A, A, B, B
            L   = lin2 + (size_t)(seg * 256) * H;
            dst = plin2 + (size_t)seg * PHS;
        }
        int i = x * 256 + tid;
        int s = i / H;
        int h = i % H;
        const float* row = att + (size_t)s * H + (seg & 1) * 256;
        const float* Lh = L + h;
        float a0 = 0.f, a1 = 0.f, a2 = 0.f, a3 = 0.f;
        for (int j = 0; j < 256; j += 4) {
            a0 = fmaf(row[j + 0], Lh[(size_t)(j + 0) * H], a0);
            a1 = fmaf(row[j + 1], Lh[(size_t)(j + 1) * H], a1);
            a2 = fmaf(row[j + 2], Lh[(size_t)(j + 2) * H], a2);
            a3 = fmaf(row[j + 3], Lh[(size_t)(j + 3) * H], a3);
        }
        dst[(size_t)s * H + h] = (a0 + a1) + (a2 + a3);
    } else {
        int idx = bx - 1300;                  // 0..63
        int j2 = (idx & 3) * 256 + tid;
        int ks = idx >> 2;                    // 0..15
        const float* row = att1 + (size_t)(ks >> 3) * PHS + (size_t)64 * H;
        int j0 = (ks & 7) * 64;
        int jbase = ks * 64;
        float a0 = 0.f, a1 = 0.f, a2 = 0.f, a3 = 0.f;
        for (int j = 0; j < 64; j += 4) {
            a0 = fmaf(row[j0 + j + 0], lin3[(size_t)(jbase + j + 0) * 1024 + j2], a0);
            a1 = fmaf(row[j0 + j + 1], lin3[(size_t)(jbase + j + 1) * 1024 + j2], a1);
            a2 = fmaf(row[j0 + j + 2], lin3[(size_t)(jbase + j + 2) * 1024 + j2], a2);
            a3 = fmaf(row[j0 + j + 3], lin3[(size_t)(jbase + j + 3) * 1024 + j2], a3);
        }
        tpart[ks * 1024 + j2] = (a0 + a1) + (a2 + a3);
    }
}

// lin2 segs 4,5 from att2 -> plin2[4],[5].  grid (130,2).
__global__ void lin2c_kernel(const float* __restrict__ att2,
                             const float* __restrict__ lin2,
                             float* __restrict__ plin2) {
    int seg = 4 + blockIdx.y;
    int i = blockIdx.x * 256 + threadIdx.x;
    int s = i / H;
    int h = i % H;
    const float* row = att2 + (size_t)s * H + (seg & 1) * 256;
    const float* Lh = lin2 + (size_t)(seg * 256) * H + h;
    float a0 = 0.f, a1 = 0.f, a2 = 0.f, a3 = 0.f;
    for (int j = 0; j < 256; j += 4) {
        a0 = fmaf(row[j + 0], Lh[(size_t)(j + 0) * H], a0);
        a1 = fmaf(row[j + 1], Lh[(size_t)(j + 1) * H], a1);
        a2 = fmaf(row[j + 2], Lh[(size_t)(j + 2) * H], a2);
        a3 = fmaf(row[j + 3], Lh[(size_t)(j + 3) * H], a3);
    }
    plin2[(size_t)seg * PHS + (size_t)s * H + h] = (a0 + a1) + (a2 + a3);
}

// ---------------------------------------------------------------------------
// Layer-3 attention (row 64 only) + lin3 slices 16..23. grid (4,8).
// ---------------------------------------------------------------------------
__global__ void attn3_lin3c_kernel(const float* __restrict__ kqvp,
                                   const float* __restrict__ lin3,
                                   float* __restrict__ tpart) {
    int tid = threadIdx.x;
    int ks  = 16 + blockIdx.y;                 // 16..23
    int j2  = blockIdx.x * 256 + tid;
    int j0  = (ks & 7) * 64;

    const float* K0 = kqvp;
    const float* K1 = kqvp + PHS;
    const float* Q0 = kqvp + 2 * (size_t)PHS;
    const float* Q1 = kqvp + 3 * (size_t)PHS;
    const float* V0 = kqvp + 4 * (size_t)PHS;
    const float* V1 = kqvp + 5 * (size_t)PHS;

    __shared__ float ka[H];
    __shared__ float sp[4 * 65];
    __shared__ float smv[S];
    __shared__ float p[S];
    __shared__ float att_s[64];

    ka[tid]       = K0[(size_t)64 * H + tid]       + K1[(size_t)64 * H + tid];
    ka[tid + 256] = K0[(size_t)64 * H + tid + 256] + K1[(size_t)64 * H + tid + 256];
    __syncthreads();

    {
        int b = tid & 63;
        int t = tid >> 6;
        sp[t * 65 + b] = score_part(Q0, Q1, ka, b, t);
        if (tid < 4) sp[tid * 65 + 64] = score_part(Q0, Q1, ka, 64, tid);
    }
    __syncthreads();

    if (tid < S) {
        smv[tid] = (sp[tid] + sp[65 + tid]) + (sp[130 + tid] + sp[195 + tid]);
    }
    __syncthreads();

    float maxv = -INFINITY;
    for (int i = 0; i < S; ++i) maxv = fmaxf(maxv, smv[i]);
    float sum = 0.0f;
    for (int i = 0; i < S; ++i) sum += expf(smv[i] - maxv);
    float inv = 1.0f / sum;
    if (tid < S) p[tid] = expf(smv[tid] - maxv) * inv;
    __syncthreads();

    if (tid < 64) {
        int hh = j0 + tid;
        float a0 = 0.f, a1 = 0.f;
#pragma unroll 4
        for (int b = 0; b < 64; b += 2) {
            a0 = fmaf(p[b    ], V0[(size_t)(b    ) * H + hh] + V1[(size_t)(b    ) * H + hh], a0);
            a1 = fmaf(p[b + 1], V0[(size_t)(b + 1) * H + hh] + V1[(size_t)(b + 1) * H + hh], a1);
        }
        a0 = fmaf(p[64], V0[(size_t)64 * H + hh] + V1[(size_t)64 * H + hh], a0);
        att_s[tid] = a0 + a1;
    }
    __syncthreads();

    int jbase = ks * 64;
    float a0 = 0.f, a1 = 0.f, a2 = 0.f, a3 = 0.f;
    for (int j = 0; j < 64; j += 4) {
        a0 = fmaf(att_s[j + 0], lin3[(size_t)(jbase + j + 0) * 1024 + j2], a0);
        a1 = fmaf(att_s[j + 1], lin3[(size_t)(jbase + j + 1) * 1024 + j2], a1);
        a2 = fmaf(att_s[j + 2], lin3[(size_t)(jbase + j + 2) * 1024 + j2], a2);
        a3 = fmaf(att_s[j + 3], lin3[(size_t)(jbase + j + 3) * 1024 + j2], a3);
    }
    tpart[ks * 1024 + j2] = (a0 + a1) + (a2 + a3);
}

// ---------------------------------------------------------------------------
__global__ void lin4_partial_kernel(const float* __restrict__ tpart,
                                    const float* __restrict__ lin4,
                                    float* __restrict__ upart) {
    __shared__ float tl[64];
    int hh = blockIdx.x * 256 + threadIdx.x;
    int ks = blockIdx.y;
    int j2base = ks * 64;

    if (threadIdx.x < 64) {
        int j2 = j2base + threadIdx.x;
        float s = 0.f;
#pragma unroll
        for (int p = 0; p < KS3; ++p) s += tpart[p * 1024 + j2];
        tl[threadIdx.x] = fmaxf(s, 0.f);
    }
    __syncthreads();

    float a0 = 0.f, a1 = 0.f, a2 = 0.f, a3 = 0.f;
    for (int j = 0; j < 64; j += 4) {
        a0 = fmaf(tl[j + 0], lin4[(size_t)(j2base + j + 0) * H + hh], a0);
        a1 = fmaf(tl[j + 1], lin4[(size_t)(j2base + j + 1) * H + hh], a1);
        a2 = fmaf(tl[j + 2], lin4[(size_t)(j2base + j + 2) * H + hh], a2);
        a3 = fmaf(tl[j + 3], lin4[(size_t)(j2base + j + 3) * H + hh], a3);
    }
    upart[ks * H + hh] = (a0 + a1) + (a2 + a3);
}

__global__ void final_out_kernel(const float* __restrict__ upart,
                                 const float* __restrict__ lin5,
                                 float* __restrict__ out) {
    __shared__ float u[H];
    __shared__ float pr[8][64];
    int tid = threadIdx.x;   // 512

    {
        float s = 0.f;
#pragma unroll
        for (int p = 0; p < KS4; ++p) s += upart[p * H + tid];
        u[tid] = tanhf(s);
    }
    __syncthreads();

    int o  = tid & 63;
    int sl = tid >> 6;
    float acc = 0.f;
    int h0 = sl * 64;
#pragma unroll 8
    for (int j = 0; j < 64; ++j) {
        acc = fmaf(u[h0 + j], lin5[(h0 + j) * 64 + o], acc);
    }
    pr[sl][o] = acc;
    __syncthreads();

    if (tid < 64) {
        float s = 0.f;
#pragma unroll
        for (int p = 0; p < 8; ++p) s += pr[p][tid];
        out[tid] = s;
    }
}

// ---------------------------------------------------------------------------
extern "C" void kernel_launch(void* const* d_in, const int* in_sizes, int n_in,
                              void* d_out, int out_size, void* d_ws, size_t ws_size,
                              hipStream_t stream) {
    const float* inputs  = (const float*)d_in[0];
    const float* emb     = (const float*)d_in[1];
    const float* wq      = (const float*)d_in[2];
    const float* wk      = (const float*)d_in[3];
    const float* wv      = (const float*)d_in[4];
    const float* linear1 = (const float*)d_in[5];
    const float* linear2 = (const float*)d_in[6];
    const float* linear3 = (const float*)d_in[7];
    const float* linear4 = (const float*)d_in[8];
    const float* linear5 = (const float*)d_in[9];
    float* out = (float*)d_out;

    float* ws    = (float*)d_ws;
    float* y     = ws;                  // PHS
    float* kqvp  = y     + PHS;         // 18*PHS
    float* att1  = kqvp  + 18 * PHS;    // 3*PHS
    float* att2  = att1  + 3 * PHS;     // PHS
    float* plin1 = att2  + PHS;         // 6*PHS
    float* plin2 = plin1 + 6 * PHS;     // 6*PHS
    float* tpart = plin2 + 6 * PHS;     // 24*1024
    float* upart = tpart + KS3 * 1024;  // 16*512

    const int nbp = PHS / 256;          // 160

    scale_embed_kernel<<<nbp, 256, 0, stream>>>(inputs, emb, y);

    // ---- Layer 1 ----
    kqv_gemm_tiled<0><<<dim3(16, 3, 3), 256, 0, stream>>>(wq, wk, wv, 0, y, kqvp);
    attn_kernel<<<dim3(S, 3), 256, 0, stream>>>(kqvp, att1);
    mega_lin_kernel<<<1364, 256, 0, stream>>>(att1, linear1, linear2, linear3,
                                              plin1, plin2, tpart);

    // ---- Layer 2 (head 2; combine1+relu inlined into As staging) ----
    kqv_gemm_tiled<1><<<dim3(16, 3, 1), 256, 0, stream>>>(wq, wk, wv, 5, plin1, kqvp);
    attn_kernel<<<dim3(S, 1), 256, 0, stream>>>(kqvp, att2);
    lin2c_kernel<<<dim3(130, 2), 256, 0, stream>>>(att2, linear2, plin2);

    // ---- Layer 3 (head 2; combine2+relu inlined) ----
    kqv_gemm_tiled<1><<<dim3(16, 3, 1), 256, 0, stream>>>(wq, wk, wv, 8, plin2, kqvp);
    attn3_lin3c_kernel<<<dim3(4, 8), 256, 0, stream>>>(kqvp, linear3, tpart);

    // ---- Final ----
    lin4_partial_kernel<<<dim3(2, KS4), 256, 0, stream>>>(tpart, linear4, upart);
    final_out_kernel<<<1, 512, 0, stream>>>(upart, linear5, out);
}

// Round 11
// 254.808 us; speedup vs baseline: 2.2079x; 1.0219x over previous
//
#include <hip/hip_runtime.h>
#include <hip/hip_bf16.h>
#include <math.h>

#define H 512
#define S 65
#define SP 80                // padded s-dimension (rows 65..79 zero/garbage)
#define HS (H * S)           // 33280
#define PHS (H * SP)         // 40960
#define KS3 24
#define KS4 16

// Layouts:
//  yT:    [SP][H]; pad rows zeroed by embed; combine writes rows <65 only.
//  kqvp:  18 arrays of PHS: ((slot*3+which)*2 + kidx)*PHS, which 0=k,1=q,2=v.
//  att1:  3 heads x PHS; att2: PHS (pad rows = poison, finite, only read as
//         harmless garbage by 4-row lin blocks whose outputs land in plin pads).
//  plin1/plin2: 6 partials x PHS each; pad rows garbage, never combined.

// ---------------------------------------------------------------------------
__global__ void scale_embed_kernel(const float* __restrict__ inp,
                                   const float* __restrict__ emb,
                                   float* __restrict__ yT) {
    int i = blockIdx.x * blockDim.x + threadIdx.x;
    if (i < PHS) {
        int s = i / H;
        int h = i % H;
        float v = 0.f;
        if (s < S) {
            float x = (s == 64) ? 1.0f : inp[s];
            v = emb[h * S + s] * x;
        }
        yT[i] = v;
    }
}

// ---------------------------------------------------------------------------
__device__ __forceinline__ void mac4(float4& c, float ax, float ay, float az,
                                     float aw, const float4& w0, const float4& w1,
                                     const float4& w2, const float4& w3) {
    c.x = fmaf(ax, w0.x, c.x); c.y = fmaf(ax, w0.y, c.y);
    c.z = fmaf(ax, w0.z, c.z); c.w = fmaf(ax, w0.w, c.w);
    c.x = fmaf(ay, w1.x, c.x); c.y = fmaf(ay, w1.y, c.y);
    c.z = fmaf(ay, w1.z, c.z); c.w = fmaf(ay, w1.w, c.w);
    c.x = fmaf(az, w2.x, c.x); c.y = fmaf(az, w2.y, c.y);
    c.z = fmaf(az, w2.z, c.z); c.w = fmaf(az, w2.w, c.w);
    c.x = fmaf(aw, w3.x, c.x); c.y = fmaf(aw, w3.y, c.y);
    c.z = fmaf(aw, w3.z, c.z); c.w = fmaf(aw, w3.w, c.w);
}

// ---------------------------------------------------------------------------
// KQV GEMM, 32-wide n-tiles (2x blocks of round-10 for latency hiding).
// C[s][n] = sum_k yT[s][k] * W[n][k].  grid.x = 16 ntiles * 2 ksplits = 32.
// As padded to stride 68 -> conflict-free reads; W staged transposed+swizzled.
// ---------------------------------------------------------------------------
__global__ void __launch_bounds__(256, 1)
kqv_gemm_tiled(const float* __restrict__ wq,
               const float* __restrict__ wk,
               const float* __restrict__ wv,
               int mat0,
               const float* __restrict__ yT,
               float* __restrict__ part) {
    int slot  = blockIdx.z;
    int which = blockIdx.y;
    int mat = mat0 + slot;
    const float* W = (which == 0 ? wk : (which == 1 ? wq : wv)) + (size_t)mat * H * H;

    int n0   = (blockIdx.x & 15) * 32;
    int kidx = blockIdx.x >> 4;

    __shared__ float Wt[64 * 32];     // [k][n swizzled]
    __shared__ float As[SP * 68];     // stride 68 = conflict-free

    int t  = threadIdx.x;
    int nq = t & 7;                   // n = n0 + 4*nq
    int g  = t >> 3;                  // 0..31; s = g, g+32, (g+64 if g<16)
    bool r2 = (g < 16);               // wave-uniform (waves 0,1)

    float4 acc0 = {0,0,0,0}, acc1 = {0,0,0,0}, acc2 = {0,0,0,0};

    for (int ch = 0; ch < 4; ++ch) {
        int kc0 = kidx * 256 + ch * 64;
#pragma unroll
        for (int c = 0; c < 2; ++c) {
            int f = c * 256 + t;
            int wn  = f >> 4;         // 0..31
            int kf4 = f & 15;
            float4 w4 = *(const float4*)(W + (size_t)(n0 + wn) * H + kc0 + 4 * kf4);
            int sw = ((wn >> 2) ^ (kf4 & 7));
            int base = (4 * kf4) * 32 + 4 * sw + (wn & 3);
            Wt[base     ] = w4.x;
            Wt[base + 32] = w4.y;
            Wt[base + 64] = w4.z;
            Wt[base + 96] = w4.w;
        }
#pragma unroll
        for (int c = 0; c < 5; ++c) {
            int f = c * 256 + t;
            int as  = f >> 4;
            int kf4 = f & 15;
            *(float4*)(&As[as * 68 + 4 * kf4]) =
                *(const float4*)(yT + (size_t)as * H + kc0 + 4 * kf4);
        }
        __syncthreads();

#pragma unroll
        for (int k4 = 0; k4 < 16; ++k4) {
            int swc = 4 * (nq ^ (k4 & 7));
            float4 w0 = *(const float4*)(&Wt[(4 * k4 + 0) * 32 + swc]);
            float4 w1 = *(const float4*)(&Wt[(4 * k4 + 1) * 32 + swc]);
            float4 w2 = *(const float4*)(&Wt[(4 * k4 + 2) * 32 + swc]);
            float4 w3 = *(const float4*)(&Wt[(4 * k4 + 3) * 32 + swc]);
            {
                float4 a = *(const float4*)(&As[g * 68 + 4 * k4]);
                mac4(acc0, a.x, a.y, a.z, a.w, w0, w1, w2, w3);
            }
            {
                float4 a = *(const float4*)(&As[(g + 32) * 68 + 4 * k4]);
                mac4(acc1, a.x, a.y, a.z, a.w, w0, w1, w2, w3);
            }
            if (r2) {
                float4 a = *(const float4*)(&As[(g + 64) * 68 + 4 * k4]);
                mac4(acc2, a.x, a.y, a.z, a.w, w0, w1, w2, w3);
            }
        }
        __syncthreads();
    }

    float* P = part + (size_t)((slot * 3 + which) * 2 + kidx) * PHS;
    *(float4*)(P + (size_t)g * H + n0 + 4 * nq) = acc0;
    *(float4*)(P + (size_t)(g + 32) * H + n0 + 4 * nq) = acc1;
    if (r2) *(float4*)(P + (size_t)(g + 64) * H + n0 + 4 * nq) = acc2;
}

// ---------------------------------------------------------------------------
__device__ __forceinline__ float score_part(const float* __restrict__ Q0,
                                            const float* __restrict__ Q1,
                                            const float* __restrict__ ka,
                                            int b, int t) {
    const float4* q0 = (const float4*)(Q0 + (size_t)b * H) + t * 32;
    const float4* q1 = (const float4*)(Q1 + (size_t)b * H) + t * 32;
    const float4* kl = (const float4*)ka + t * 32;
    float4 c0 = {0,0,0,0}, c1 = {0,0,0,0};
#pragma unroll
    for (int u = 0; u < 32; u += 2) {
        float4 qa = q0[u], qb = q1[u], k0 = kl[u];
        float4 qc = q0[u+1], qd = q1[u+1], k1 = kl[u+1];
        c0.x = fmaf(k0.x, qa.x + qb.x, c0.x);
        c0.y = fmaf(k0.y, qa.y + qb.y, c0.y);
        c0.z = fmaf(k0.z, qa.z + qb.z, c0.z);
        c0.w = fmaf(k0.w, qa.w + qb.w, c0.w);
        c1.x = fmaf(k1.x, qc.x + qd.x, c1.x);
        c1.y = fmaf(k1.y, qc.y + qd.y, c1.y);
        c1.z = fmaf(k1.z, qc.z + qd.z, c1.z);
        c1.w = fmaf(k1.w, qc.w + qd.w, c1.w);
    }
    return ((c0.x + c0.y) + (c0.z + c0.w)) + ((c1.x + c1.y) + (c1.z + c1.w));
}

// ---------------------------------------------------------------------------
__global__ void attn_kernel(const float* __restrict__ kqvp,
                            float* __restrict__ att) {
    int a = blockIdx.x;
    int slot = blockIdx.y;
    int tid = threadIdx.x;   // 256

    const float* base = kqvp + (size_t)slot * 6 * PHS;
    const float* K0 = base;
    const float* K1 = base + PHS;
    const float* Q0 = base + 2 * (size_t)PHS;
    const float* Q1 = base + 3 * (size_t)PHS;
    const float* V0 = base + 4 * (size_t)PHS;
    const float* V1 = base + 5 * (size_t)PHS;
    float* ao = att + (size_t)slot * PHS + (size_t)a * H;

    __shared__ float ka[H];
    __shared__ float sp[4 * 65];
    __shared__ float smv[S];
    __shared__ float p[S];

    ka[tid]       = K0[(size_t)a * H + tid]       + K1[(size_t)a * H + tid];
    ka[tid + 256] = K0[(size_t)a * H + tid + 256] + K1[(size_t)a * H + tid + 256];
    __syncthreads();

    {
        int b = tid & 63;
        int t = tid >> 6;          // wave-uniform
        sp[t * 65 + b] = score_part(Q0, Q1, ka, b, t);
        if (tid < 4) sp[tid * 65 + 64] = score_part(Q0, Q1, ka, 64, tid);
    }
    __syncthreads();

    if (tid < S) {
        smv[tid] = (sp[tid] + sp[65 + tid]) + (sp[130 + tid] + sp[195 + tid]);
    }
    __syncthreads();

    float maxv = -INFINITY;
    for (int i = 0; i < S; ++i) maxv = fmaxf(maxv, smv[i]);
    float sum = 0.0f;
    for (int i = 0; i < S; ++i) sum += expf(smv[i] - maxv);
    float inv = 1.0f / sum;
    if (tid < S) p[tid] = expf(smv[tid] - maxv) * inv;
    __syncthreads();

#pragma unroll
    for (int rep = 0; rep < 2; ++rep) {
        int hh = tid + rep * 256;
        float a0 = 0.f, a1 = 0.f;
#pragma unroll 4
        for (int b = 0; b < 64; b += 2) {
            a0 = fmaf(p[b    ], V0[(size_t)(b    ) * H + hh] + V1[(size_t)(b    ) * H + hh], a0);
            a1 = fmaf(p[b + 1], V0[(size_t)(b + 1) * H + hh] + V1[(size_t)(b + 1) * H + hh], a1);
        }
        a0 = fmaf(p[64], V0[(size_t)64 * H + hh] + V1[(size_t)64 * H + hh], a0);
        ao[hh] = a0 + a1;
    }
}

// ---------------------------------------------------------------------------
// 4-row linear block: rows s0..s0+3 x 512 h of one 256-k segment.
// float4 weight loads (16 B/lane); 2-way j-split reduced via LDS.
// Rows >= 65 read att poison (finite) and write plin pad rows (never read).
// ---------------------------------------------------------------------------
__device__ __forceinline__ void lin4row_dev(const float* __restrict__ att,
                                            int col0,
                                            const float* __restrict__ L,
                                            float* __restrict__ dst,
                                            int s0, int tid) {
    __shared__ float Ar[4 * 256];
    __shared__ float4 red[4 * 128];

    {
        int rr = tid >> 6;
        int cc = tid & 63;
        *(float4*)(&Ar[rr * 256 + cc * 4]) =
            *(const float4*)(att + (size_t)(s0 + rr) * H + col0 + cc * 4);
    }
    __syncthreads();

    int h4 = (tid & 127) * 4;
    int jh = tid >> 7;             // wave-uniform (waves 0,1 vs 2,3)
    const float* Lj = L + (size_t)(jh * 128) * H + h4;
    const float* A0 = Ar + jh * 128;

    float4 c0 = {0,0,0,0}, c1 = {0,0,0,0}, c2 = {0,0,0,0}, c3 = {0,0,0,0};
#pragma unroll 8
    for (int j = 0; j < 128; ++j) {
        float4 L4 = *(const float4*)(Lj + (size_t)j * H);
        float a0 = A0[j], a1 = A0[256 + j], a2 = A0[512 + j], a3 = A0[768 + j];
        c0.x = fmaf(a0, L4.x, c0.x); c0.y = fmaf(a0, L4.y, c0.y);
        c0.z = fmaf(a0, L4.z, c0.z); c0.w = fmaf(a0, L4.w, c0.w);
        c1.x = fmaf(a1, L4.x, c1.x); c1.y = fmaf(a1, L4.y, c1.y);
        c1.z = fmaf(a1, L4.z, c1.z); c1.w = fmaf(a1, L4.w, c1.w);
        c2.x = fmaf(a2, L4.x, c2.x); c2.y = fmaf(a2, L4.y, c2.y);
        c2.z = fmaf(a2, L4.z, c2.z); c2.w = fmaf(a2, L4.w, c2.w);
        c3.x = fmaf(a3, L4.x, c3.x); c3.y = fmaf(a3, L4.y, c3.y);
        c3.z = fmaf(a3, L4.z, c3.z); c3.w = fmaf(a3, L4.w, c3.w);
    }

    if (jh == 1) {
        int x = tid & 127;
        red[x] = c0; red[128 + x] = c1; red[256 + x] = c2; red[384 + x] = c3;
    }
    __syncthreads();
    if (jh == 0) {
        float4 r0 = red[tid], r1 = red[128 + tid], r2 = red[256 + tid], r3 = red[384 + tid];
        c0.x += r0.x; c0.y += r0.y; c0.z += r0.z; c0.w += r0.w;
        c1.x += r1.x; c1.y += r1.y; c1.z += r1.z; c1.w += r1.w;
        c2.x += r2.x; c2.y += r2.y; c2.z += r2.z; c2.w += r2.w;
        c3.x += r3.x; c3.y += r3.y; c3.z += r3.z; c3.w += r3.w;
        *(float4*)(dst + (size_t)(s0 + 0) * H + h4) = c0;
        *(float4*)(dst + (size_t)(s0 + 1) * H + h4) = c1;
        *(float4*)(dst + (size_t)(s0 + 2) * H + h4) = c2;
        *(float4*)(dst + (size_t)(s0 + 3) * H + h4) = c3;
    }
}

// ---------------------------------------------------------------------------
// Mega linear: lin1 (6 segs) + lin2 segs 0..3 (4-row blocks, 17 pairs each)
// + lin3 row-64 K-slices 0..15.  Grid 234.
// ---------------------------------------------------------------------------
__global__ void mega_lin_kernel(const float* __restrict__ att1,
                                const float* __restrict__ lin1,
                                const float* __restrict__ lin2,
                                const float* __restrict__ lin3,
                                float* __restrict__ plin1,
                                float* __restrict__ plin2,
                                float* __restrict__ tpart) {
    int bx = blockIdx.x;
    int tid = threadIdx.x;

    if (bx < 170) {
        int seg = bx / 17;      // 0..9
        int p   = bx % 17;
        const float* att;
        const float* L;
        float* dst;
        if (seg < 6) {
            att = att1 + (size_t)(seg >> 1) * PHS;
            L   = lin1 + (size_t)(seg * 256) * H;
            dst = plin1 + (size_t)seg * PHS;
        } else {
            int s2 = seg - 6;
            att = att1 + (size_t)(s2 >> 1) * PHS;
            L   = lin2 + (size_t)(s2 * 256) * H;
            dst = plin2 + (size_t)s2 * PHS;
        }
        lin4row_dev(att, (seg & 1) * 256, L, dst, p * 4, tid);
    } else {
        int idx = bx - 170;                   // 0..63
        int j2 = (idx & 3) * 256 + tid;
        int ks = idx >> 2;                    // 0..15
        const float* row = att1 + (size_t)(ks >> 3) * PHS + (size_t)64 * H;
        int j0 = (ks & 7) * 64;
        int jbase = ks * 64;
        float a0 = 0.f, a1 = 0.f, a2 = 0.f, a3 = 0.f;
        for (int j = 0; j < 64; j += 4) {
            a0 = fmaf(row[j0 + j + 0], lin3[(size_t)(jbase + j + 0) * 1024 + j2], a0);
            a1 = fmaf(row[j0 + j + 1], lin3[(size_t)(jbase + j + 1) * 1024 + j2], a1);
            a2 = fmaf(row[j0 + j + 2], lin3[(size_t)(jbase + j + 2) * 1024 + j2], a2);
            a3 = fmaf(row[j0 + j + 3], lin3[(size_t)(jbase + j + 3) * 1024 + j2], a3);
        }
        tpart[ks * 1024 + j2] = (a0 + a1) + (a2 + a3);
    }
}

// lin2 segs 4,5 from att2.  Grid 34.
__global__ void lin2c_kernel(const float* __restrict__ att2,
                             const float* __restrict__ lin2,
                             float* __restrict__ plin2) {
    int seg = 4 + blockIdx.x / 17;
    int p   = blockIdx.x % 17;
    lin4row_dev(att2, (seg & 1) * 256, lin2 + (size_t)(seg * 256) * H,
                plin2 + (size_t)seg * PHS, p * 4, threadIdx.x);
}

// 6-way partial sum + relu -> yT rows <65 (pad rows stay zero from embed)
__global__ void combine6_relu_kernel(const float* __restrict__ part,
                                     float* __restrict__ yT) {
    int i = blockIdx.x * 256 + threadIdx.x;   // 130*256 == HS exactly
    float s = 0.f;
#pragma unroll
    for (int p = 0; p < 6; ++p) s += part[(size_t)p * PHS + i];
    yT[i] = fmaxf(s, 0.0f);
}

// ---------------------------------------------------------------------------
// Layer-3 attention (row 64 only) + lin3 slices 16..23. grid (4,8).
// ---------------------------------------------------------------------------
__global__ void attn3_lin3c_kernel(const float* __restrict__ kqvp,
                                   const float* __restrict__ lin3,
                                   float* __restrict__ tpart) {
    int tid = threadIdx.x;
    int ks  = 16 + blockIdx.y;
    int j2  = blockIdx.x * 256 + tid;
    int j0  = (ks & 7) * 64;

    const float* K0 = kqvp;
    const float* K1 = kqvp + PHS;
    const float* Q0 = kqvp + 2 * (size_t)PHS;
    const float* Q1 = kqvp + 3 * (size_t)PHS;
    const float* V0 = kqvp + 4 * (size_t)PHS;
    const float* V1 = kqvp + 5 * (size_t)PHS;

    __shared__ float ka[H];
    __shared__ float sp[4 * 65];
    __shared__ float smv[S];
    __shared__ float p[S];
    __shared__ float att_s[64];

    ka[tid]       = K0[(size_t)64 * H + tid]       + K1[(size_t)64 * H + tid];
    ka[tid + 256] = K0[(size_t)64 * H + tid + 256] + K1[(size_t)64 * H + tid + 256];
    __syncthreads();

    {
        int b = tid & 63;
        int t = tid >> 6;
        sp[t * 65 + b] = score_part(Q0, Q1, ka, b, t);
        if (tid < 4) sp[tid * 65 + 64] = score_part(Q0, Q1, ka, 64, tid);
    }
    __syncthreads();

    if (tid < S) {
        smv[tid] = (sp[tid] + sp[65 + tid]) + (sp[130 + tid] + sp[195 + tid]);
    }
    __syncthreads();

    float maxv = -INFINITY;
    for (int i = 0; i < S; ++i) maxv = fmaxf(maxv, smv[i]);
    float sum = 0.0f;
    for (int i = 0; i < S; ++i) sum += expf(smv[i] - maxv);
    float inv = 1.0f / sum;
    if (tid < S) p[tid] = expf(smv[tid] - maxv) * inv;
    __syncthreads();

    if (tid < 64) {
        int hh = j0 + tid;
        float a0 = 0.f, a1 = 0.f;
#pragma unroll 4
        for (int b = 0; b < 64; b += 2) {
            a0 = fmaf(p[b    ], V0[(size_t)(b    ) * H + hh] + V1[(size_t)(b    ) * H + hh], a0);
            a1 = fmaf(p[b + 1], V0[(size_t)(b + 1) * H + hh] + V1[(size_t)(b + 1) * H + hh], a1);
        }
        a0 = fmaf(p[64], V0[(size_t)64 * H + hh] + V1[(size_t)64 * H + hh], a0);
        att_s[tid] = a0 + a1;
    }
    __syncthreads();

    int jbase = ks * 64;
    float a0 = 0.f, a1 = 0.f, a2 = 0.f, a3 = 0.f;
    for (int j = 0; j < 64; j += 4) {
        a0 = fmaf(att_s[j + 0], lin3[(size_t)(jbase + j + 0) * 1024 + j2], a0);
        a1 = fmaf(att_s[j + 1], lin3[(size_t)(jbase + j + 1) * 1024 + j2], a1);
        a2 = fmaf(att_s[j + 2], lin3[(size_t)(jbase + j + 2) * 1024 + j2], a2);
        a3 = fmaf(att_s[j + 3], lin3[(size_t)(jbase + j + 3) * 1024 + j2], a3);
    }
    tpart[ks * 1024 + j2] = (a0 + a1) + (a2 + a3);
}

// ---------------------------------------------------------------------------
__global__ void lin4_partial_kernel(const float* __restrict__ tpart,
                                    const float* __restrict__ lin4,
                                    float* __restrict__ upart) {
    __shared__ float tl[64];
    int hh = blockIdx.x * 256 + threadIdx.x;
    int ks = blockIdx.y;
    int j2base = ks * 64;

    if (threadIdx.x < 64) {
        int j2 = j2base + threadIdx.x;
        float s = 0.f;
#pragma unroll
        for (int p = 0; p < KS3; ++p) s += tpart[p * 1024 + j2];
        tl[threadIdx.x] = fmaxf(s, 0.f);
    }
    __syncthreads();

    float a0 = 0.f, a1 = 0.f, a2 = 0.f, a3 = 0.f;
    for (int j = 0; j < 64; j += 4) {
        a0 = fmaf(tl[j + 0], lin4[(size_t)(j2base + j + 0) * H + hh], a0);
        a1 = fmaf(tl[j + 1], lin4[(size_t)(j2base + j + 1) * H + hh], a1);
        a2 = fmaf(tl[j + 2], lin4[(size_t)(j2base + j + 2) * H + hh], a2);
        a3 = fmaf(tl[j + 3], lin4[(size_t)(j2base + j + 3) * H + hh], a3);
    }
    upart[ks * H + hh] = (a0 + a1) + (a2 + a3);
}

__global__ void final_out_kernel(const float* __restrict__ upart,
                                 const float* __restrict__ lin5,
                                 float* __restrict__ out) {
    __shared__ float u[H];
    __shared__ float pr[8][64];
    int tid = threadIdx.x;   // 512

    {
        float s = 0.f;
#pragma unroll
        for (int p = 0; p < KS4; ++p) s += upart[p * H + tid];
        u[tid] = tanhf(s);
    }
    __syncthreads();

    int o  = tid & 63;
    int sl = tid >> 6;
    float acc = 0.f;
    int h0 = sl * 64;
#pragma unroll 8
    for (int j = 0; j < 64; ++j) {
        acc = fmaf(u[h0 + j], lin5[(h0 + j) * 64 + o], acc);
    }
    pr[sl][o] = acc;
    __syncthreads();

    if (tid < 64) {
        float s = 0.f;
#pragma unroll
        for (int p = 0; p < 8; ++p) s += pr[p][tid];
        out[tid] = s;
    }
}

// ---------------------------------------------------------------------------
extern "C" void kernel_launch(void* const* d_in, const int* in_sizes, int n_in,
                              void* d_out, int out_size, void* d_ws, size_t ws_size,
                              hipStream_t stream) {
    const float* inputs  = (const float*)d_in[0];
    const float* emb     = (const float*)d_in[1];
    const float* wq      = (const float*)d_in[2];
    const float* wk      = (const float*)d_in[3];
    const float* wv      = (const float*)d_in[4];
    const float* linear1 = (const float*)d_in[5];
    const float* linear2 = (const float*)d_in[6];
    const float* linear3 = (const float*)d_in[7];
    const float* linear4 = (const float*)d_in[8];
    const float* linear5 = (const float*)d_in[9];
    float* out = (float*)d_out;

    float* ws    = (float*)d_ws;
    float* y     = ws;                  // PHS
    float* kqvp  = y     + PHS;         // 18*PHS
    float* att1  = kqvp  + 18 * PHS;    // 3*PHS
    float* att2  = att1  + 3 * PHS;     // PHS
    float* plin1 = att2  + PHS;         // 6*PHS
    float* plin2 = plin1 + 6 * PHS;     // 6*PHS
    float* tpart = plin2 + 6 * PHS;     // 24*1024
    float* upart = tpart + KS3 * 1024;  // 16*512

    const int nb  = HS / 256;           // 130
    const int nbp = PHS / 256;          // 160

    scale_embed_kernel<<<nbp, 256, 0, stream>>>(inputs, emb, y);

    // ---- Layer 1 ----
    kqv_gemm_tiled<<<dim3(32, 3, 3), 256, 0, stream>>>(wq, wk, wv, 0, y, kqvp);
    attn_kernel<<<dim3(S, 3), 256, 0, stream>>>(kqvp, att1);
    mega_lin_kernel<<<234, 256, 0, stream>>>(att1, linear1, linear2, linear3,
                                             plin1, plin2, tpart);
    combine6_relu_kernel<<<nb, 256, 0, stream>>>(plin1, y);

    // ---- Layer 2 (head 2 only) ----
    kqv_gemm_tiled<<<dim3(32, 3, 1), 256, 0, stream>>>(wq, wk, wv, 5, y, kqvp);
    attn_kernel<<<dim3(S, 1), 256, 0, stream>>>(kqvp, att2);
    lin2c_kernel<<<34, 256, 0, stream>>>(att2, linear2, plin2);
    combine6_relu_kernel<<<nb, 256, 0, stream>>>(plin2, y);

    // ---- Layer 3 (head 2, row 64) + lin3 tail ----
    kqv_gemm_tiled<<<dim3(32, 3, 1), 256, 0, stream>>>(wq, wk, wv, 8, y, kqvp);
    attn3_lin3c_kernel<<<dim3(4, 8), 256, 0, stream>>>(kqvp, linear3, tpart);

    // ---- Final ----
    lin4_partial_kernel<<<dim3(2, KS4), 256, 0, stream>>>(tpart, linear4, upart);
    final_out_kernel<<<1, 512, 0, stream>>>(upart, linear5, out);
}